// Round 1
// baseline (833.962 us; speedup 1.0000x reference)
//
#include <hip/hip_runtime.h>
#include <cstdint>
#include <cstddef>

typedef short short8 __attribute__((ext_vector_type(8)));
typedef short short4v __attribute__((ext_vector_type(4)));
typedef float f32x4 __attribute__((ext_vector_type(4)));
typedef __bf16 bf16x8 __attribute__((ext_vector_type(8)));

__device__ __forceinline__ unsigned short f2bu(float f) {
  union { float f; unsigned u; } v; v.f = f;
  unsigned r = v.u + 0x7FFFu + ((v.u >> 16) & 1u);
  return (unsigned short)(r >> 16);
}
__device__ __forceinline__ float b2f(unsigned short h) {
  union { unsigned u; float f; } v; v.u = ((unsigned)h) << 16;
  return v.f;
}

__device__ __forceinline__ f32x4 mfma16(short8 a, short8 b, f32x4 c) {
  return __builtin_amdgcn_mfma_f32_16x16x32_bf16(
      __builtin_bit_cast(bf16x8, a), __builtin_bit_cast(bf16x8, b), c, 0, 0, 0);
}

// ---------------- weight transpose + bf16 cast: wt[n*K+k] = w[k*N+n] ------
__global__ void k_wt(const float* __restrict__ w, short* __restrict__ wt, int K, int N) {
  int t = blockIdx.x * 256 + threadIdx.x;
  if (t >= K * N) return;
  int n = t / K;
  int k = t - n * K;
  wt[t] = (short)f2bu(w[(size_t)k * N + n]);
}

// ---------------- fused 2-layer MLP (g_u): concat(tab0[i0],tab1[i1]) 512->256 relu ->256, bf16 out
__global__ __launch_bounds__(256, 2) void k_mlp2(
    const int* __restrict__ idxpair,
    const float* __restrict__ tab0,
    const float* __restrict__ tab1,
    const short* __restrict__ w1t, const float* __restrict__ b1,
    const short* __restrict__ w2t, const float* __restrict__ b2,
    short* __restrict__ out)
{
  __shared__ __align__(16) short smem[29696];
  short (*A)[40]   = (short(*)[40])smem;            // 64 x 40
  short (*Bt)[40]  = (short(*)[40])(smem + 2560);   // 256 x 40
  short (*Hh)[264] = (short(*)[264])(smem + 12800); // 64 x 264

  const int tid  = threadIdx.x;
  const int lane = tid & 63;
  const int wave = tid >> 6;
  const int m0   = blockIdx.x << 6;
  const int arow = tid >> 2;
  const int acol8 = (tid & 3) << 3;
  const int lrow = lane & 15;
  const int lk8  = (lane >> 4) << 3;
  const int rq   = (lane >> 4) << 2;
  const int nb   = wave << 6;

  const int r = m0 + arow;
  const int i0 = idxpair[2 * r];
  const int i1 = idxpair[2 * r + 1];
  const float* src0 = tab0 + (size_t)i0 * 256;
  const float* src1 = tab1 + (size_t)i1 * 256;

  const f32x4 fz = {0.f, 0.f, 0.f, 0.f};
  f32x4 acc[4][4];
#pragma unroll
  for (int mi = 0; mi < 4; ++mi)
#pragma unroll
    for (int ni = 0; ni < 4; ++ni) acc[mi][ni] = fz;

  for (int ks = 0; ks < 16; ++ks) {
    const int kg = (ks << 5) + acol8;
    const float* sp = (kg < 256) ? (src0 + kg) : (src1 + (kg - 256));
    float4 v0 = *(const float4*)(sp);
    float4 v1 = *(const float4*)(sp + 4);
    short8 av;
    av[0] = (short)f2bu(v0.x); av[1] = (short)f2bu(v0.y);
    av[2] = (short)f2bu(v0.z); av[3] = (short)f2bu(v0.w);
    av[4] = (short)f2bu(v1.x); av[5] = (short)f2bu(v1.y);
    av[6] = (short)f2bu(v1.z); av[7] = (short)f2bu(v1.w);
    *(short8*)&A[arow][acol8] = av;
    const short* wsrc = w1t + tid * 512 + (ks << 5);
    *(short8*)&Bt[tid][0]  = *(const short8*)(wsrc);
    *(short8*)&Bt[tid][8]  = *(const short8*)(wsrc + 8);
    *(short8*)&Bt[tid][16] = *(const short8*)(wsrc + 16);
    *(short8*)&Bt[tid][24] = *(const short8*)(wsrc + 24);
    __syncthreads();
    short8 af[4], bv[4];
#pragma unroll
    for (int mi = 0; mi < 4; ++mi) af[mi] = *(short8*)&A[mi * 16 + lrow][lk8];
#pragma unroll
    for (int ni = 0; ni < 4; ++ni) bv[ni] = *(short8*)&Bt[nb + ni * 16 + lrow][lk8];
#pragma unroll
    for (int mi = 0; mi < 4; ++mi)
#pragma unroll
      for (int ni = 0; ni < 4; ++ni)
        acc[mi][ni] = mfma16(af[mi], bv[ni], acc[mi][ni]);
    __syncthreads();
  }

  // hidden = relu(acc + b1) -> LDS (bf16)
#pragma unroll
  for (int ni = 0; ni < 4; ++ni) {
    const int col = nb + ni * 16 + lrow;
    const float bias = b1[col];
#pragma unroll
    for (int mi = 0; mi < 4; ++mi)
#pragma unroll
      for (int j = 0; j < 4; ++j) {
        const int row = mi * 16 + rq + j;
        Hh[row][col] = (short)f2bu(fmaxf(acc[mi][ni][j] + bias, 0.f));
      }
  }

#pragma unroll
  for (int mi = 0; mi < 4; ++mi)
#pragma unroll
    for (int ni = 0; ni < 4; ++ni) acc[mi][ni] = fz;

  for (int ks = 0; ks < 8; ++ks) {
    const short* wsrc = w2t + tid * 256 + (ks << 5);
    *(short8*)&Bt[tid][0]  = *(const short8*)(wsrc);
    *(short8*)&Bt[tid][8]  = *(const short8*)(wsrc + 8);
    *(short8*)&Bt[tid][16] = *(const short8*)(wsrc + 16);
    *(short8*)&Bt[tid][24] = *(const short8*)(wsrc + 24);
    __syncthreads();
    short8 af[4], bv[4];
#pragma unroll
    for (int mi = 0; mi < 4; ++mi) af[mi] = *(short8*)&Hh[mi * 16 + lrow][(ks << 5) + lk8];
#pragma unroll
    for (int ni = 0; ni < 4; ++ni) bv[ni] = *(short8*)&Bt[nb + ni * 16 + lrow][lk8];
#pragma unroll
    for (int mi = 0; mi < 4; ++mi)
#pragma unroll
      for (int ni = 0; ni < 4; ++ni)
        acc[mi][ni] = mfma16(af[mi], bv[ni], acc[mi][ni]);
    __syncthreads();
  }

#pragma unroll
  for (int ni = 0; ni < 4; ++ni) {
    const int col = nb + ni * 16 + lrow;
    const float bias = b2[col];
#pragma unroll
    for (int mi = 0; mi < 4; ++mi)
#pragma unroll
      for (int j = 0; j < 4; ++j) {
        const int row = mi * 16 + rq + j;
        out[(size_t)(m0 + row) * 256 + col] = (short)f2bu(acc[mi][ni][j] + bias);
      }
  }
}

// ---------------- attention-score MLP: concat(first[r], mask*item_table[idx]) 512->256 relu ->16
// VAR 1: part1 (idx=iids[r/12], mask=i_user_pad[2r]>0)
// VAR 2: part2 (idx=i_item_pad[r/12], mask=i_item_user_pad[2r]>0)
// VAR 3: attii (idx=i_item_pad[r], no mask)
template <int VAR>
__global__ __launch_bounds__(256, 2) void k_att(
    const short* __restrict__ first,
    const float* __restrict__ item_table,
    const int* __restrict__ iids,
    const int* __restrict__ i_user_pad,
    const int* __restrict__ i_item_pad,
    const int* __restrict__ i_item_user_pad,
    const short* __restrict__ w1t, const float* __restrict__ b1,
    const short* __restrict__ w2t, const float* __restrict__ b2,
    float* __restrict__ miu_out)
{
  __shared__ __align__(16) short smem[29696];
  short (*A)[40]   = (short(*)[40])smem;
  short (*Bt)[40]  = (short(*)[40])(smem + 2560);
  short (*W2)[264] = (short(*)[264])smem;           // aliases A/Bt after layer 1
  short (*Hh)[264] = (short(*)[264])(smem + 12800);

  const int tid  = threadIdx.x;
  const int lane = tid & 63;
  const int wave = tid >> 6;
  const int m0   = blockIdx.x << 6;
  const int arow = tid >> 2;
  const int acol8 = (tid & 3) << 3;
  const int lrow = lane & 15;
  const int lk8  = (lane >> 4) << 3;
  const int rq   = (lane >> 4) << 2;
  const int nb   = wave << 6;

  const int r = m0 + arow;
  int sidx; float maskv;
  if (VAR == 1)      { sidx = iids[r / 12];       maskv = (i_user_pad[2 * r] > 0) ? 1.f : 0.f; }
  else if (VAR == 2) { sidx = i_item_pad[r / 12]; maskv = (i_item_user_pad[2 * r] > 0) ? 1.f : 0.f; }
  else               { sidx = i_item_pad[r];      maskv = 1.f; }
  const float* src1 = item_table + (size_t)sidx * 256;
  const short* fsrc = first + (size_t)r * 256;

  const f32x4 fz = {0.f, 0.f, 0.f, 0.f};
  f32x4 acc[4][4];
#pragma unroll
  for (int mi = 0; mi < 4; ++mi)
#pragma unroll
    for (int ni = 0; ni < 4; ++ni) acc[mi][ni] = fz;

  for (int ks = 0; ks < 16; ++ks) {
    const int kg = (ks << 5) + acol8;
    short8 av;
    if (kg < 256) {
      av = *(const short8*)(fsrc + kg);
    } else {
      float4 v0 = *(const float4*)(src1 + (kg - 256));
      float4 v1 = *(const float4*)(src1 + (kg - 252));
      av[0] = (short)f2bu(v0.x * maskv); av[1] = (short)f2bu(v0.y * maskv);
      av[2] = (short)f2bu(v0.z * maskv); av[3] = (short)f2bu(v0.w * maskv);
      av[4] = (short)f2bu(v1.x * maskv); av[5] = (short)f2bu(v1.y * maskv);
      av[6] = (short)f2bu(v1.z * maskv); av[7] = (short)f2bu(v1.w * maskv);
    }
    *(short8*)&A[arow][acol8] = av;
    const short* wsrc = w1t + tid * 512 + (ks << 5);
    *(short8*)&Bt[tid][0]  = *(const short8*)(wsrc);
    *(short8*)&Bt[tid][8]  = *(const short8*)(wsrc + 8);
    *(short8*)&Bt[tid][16] = *(const short8*)(wsrc + 16);
    *(short8*)&Bt[tid][24] = *(const short8*)(wsrc + 24);
    __syncthreads();
    short8 af[4], bv[4];
#pragma unroll
    for (int mi = 0; mi < 4; ++mi) af[mi] = *(short8*)&A[mi * 16 + lrow][lk8];
#pragma unroll
    for (int ni = 0; ni < 4; ++ni) bv[ni] = *(short8*)&Bt[nb + ni * 16 + lrow][lk8];
#pragma unroll
    for (int mi = 0; mi < 4; ++mi)
#pragma unroll
      for (int ni = 0; ni < 4; ++ni)
        acc[mi][ni] = mfma16(af[mi], bv[ni], acc[mi][ni]);
    __syncthreads();
  }

#pragma unroll
  for (int ni = 0; ni < 4; ++ni) {
    const int col = nb + ni * 16 + lrow;
    const float bias = b1[col];
#pragma unroll
    for (int mi = 0; mi < 4; ++mi)
#pragma unroll
      for (int j = 0; j < 4; ++j) {
        const int row = mi * 16 + rq + j;
        Hh[row][col] = (short)f2bu(fmaxf(acc[mi][ni][j] + bias, 0.f));
      }
  }

  // stage W2 (16 x 256) into the aliased region — safe: A/Bt last read before final barrier
  {
    const int rw  = tid & 15;
    const int seg = (tid >> 4) << 4;
    const short* s = w2t + rw * 256 + seg;
    *(short8*)&W2[rw][seg]     = *(const short8*)(s);
    *(short8*)&W2[rw][seg + 8] = *(const short8*)(s + 8);
  }
  __syncthreads();

  f32x4 acc2 = fz;
#pragma unroll
  for (int ks = 0; ks < 8; ++ks) {
    short8 af = *(short8*)&Hh[(wave << 4) + lrow][(ks << 5) + lk8];
    short8 bv = *(short8*)&W2[lrow][(ks << 5) + lk8];
    acc2 = mfma16(af, bv, acc2);
  }
  const float bias = b2[lrow];
#pragma unroll
  for (int j = 0; j < 4; ++j) {
    const int row = (wave << 4) + rq + j;
    miu_out[(size_t)(m0 + row) * 16 + lrow] = acc2[j] + bias;
  }
}

// ---------------- single-layer GEMM 256->256 + bias + relu, bf16 in/out ----
__global__ __launch_bounds__(256, 2) void k_gemm1(
    const short* __restrict__ Abf, const short* __restrict__ wt,
    const float* __restrict__ bias, short* __restrict__ out)
{
  __shared__ __align__(16) short smem[12800];
  short (*A)[40]  = (short(*)[40])smem;
  short (*Bt)[40] = (short(*)[40])(smem + 2560);

  const int tid  = threadIdx.x;
  const int lane = tid & 63;
  const int wave = tid >> 6;
  const int m0   = blockIdx.x << 6;
  const int arow = tid >> 2;
  const int acol8 = (tid & 3) << 3;
  const int lrow = lane & 15;
  const int lk8  = (lane >> 4) << 3;
  const int rq   = (lane >> 4) << 2;
  const int nb   = wave << 6;
  const int r = m0 + arow;

  const f32x4 fz = {0.f, 0.f, 0.f, 0.f};
  f32x4 acc[4][4];
#pragma unroll
  for (int mi = 0; mi < 4; ++mi)
#pragma unroll
    for (int ni = 0; ni < 4; ++ni) acc[mi][ni] = fz;

  for (int ks = 0; ks < 8; ++ks) {
    *(short8*)&A[arow][acol8] = *(const short8*)(Abf + (size_t)r * 256 + (ks << 5) + acol8);
    const short* wsrc = wt + tid * 256 + (ks << 5);
    *(short8*)&Bt[tid][0]  = *(const short8*)(wsrc);
    *(short8*)&Bt[tid][8]  = *(const short8*)(wsrc + 8);
    *(short8*)&Bt[tid][16] = *(const short8*)(wsrc + 16);
    *(short8*)&Bt[tid][24] = *(const short8*)(wsrc + 24);
    __syncthreads();
    short8 af[4], bv[4];
#pragma unroll
    for (int mi = 0; mi < 4; ++mi) af[mi] = *(short8*)&A[mi * 16 + lrow][lk8];
#pragma unroll
    for (int ni = 0; ni < 4; ++ni) bv[ni] = *(short8*)&Bt[nb + ni * 16 + lrow][lk8];
#pragma unroll
    for (int mi = 0; mi < 4; ++mi)
#pragma unroll
      for (int ni = 0; ni < 4; ++ni)
        acc[mi][ni] = mfma16(af[mi], bv[ni], acc[mi][ni]);
    __syncthreads();
  }

#pragma unroll
  for (int ni = 0; ni < 4; ++ni) {
    const int col = nb + ni * 16 + lrow;
    const float b = bias[col];
#pragma unroll
    for (int mi = 0; mi < 4; ++mi)
#pragma unroll
      for (int j = 0; j < 4; ++j) {
        const int row = mi * 16 + rq + j;
        out[(size_t)(m0 + row) * 256 + col] = (short)f2bu(fmaxf(acc[mi][ni][j] + b, 0.f));
      }
  }
}

// ---------------- fused 3-layer comb MLP: concat(hju,hjv) 512->256->256->256, relu each, f32 out
__global__ __launch_bounds__(256, 2) void k_comb(
    const short* __restrict__ hju, const short* __restrict__ hjv,
    const short* __restrict__ w1t, const float* __restrict__ b1,
    const short* __restrict__ w2t, const float* __restrict__ b2,
    const short* __restrict__ w3t, const float* __restrict__ b3,
    float* __restrict__ out)
{
  __shared__ __align__(16) short smem[29696];
  short (*A)[40]   = (short(*)[40])smem;
  short (*Bt)[40]  = (short(*)[40])(smem + 2560);
  short (*Hh)[264] = (short(*)[264])(smem + 12800);

  const int tid  = threadIdx.x;
  const int lane = tid & 63;
  const int wave = tid >> 6;
  const int m0   = blockIdx.x << 6;
  const int arow = tid >> 2;
  const int acol8 = (tid & 3) << 3;
  const int lrow = lane & 15;
  const int lk8  = (lane >> 4) << 3;
  const int rq   = (lane >> 4) << 2;
  const int nb   = wave << 6;
  const int r = m0 + arow;

  const f32x4 fz = {0.f, 0.f, 0.f, 0.f};
  f32x4 acc[4][4];
#pragma unroll
  for (int mi = 0; mi < 4; ++mi)
#pragma unroll
    for (int ni = 0; ni < 4; ++ni) acc[mi][ni] = fz;

  // layer 1 (K=512)
  for (int ks = 0; ks < 16; ++ks) {
    const int kg = (ks << 5) + acol8;
    short8 av = (kg < 256) ? *(const short8*)(hju + (size_t)r * 256 + kg)
                           : *(const short8*)(hjv + (size_t)r * 256 + (kg - 256));
    *(short8*)&A[arow][acol8] = av;
    const short* wsrc = w1t + tid * 512 + (ks << 5);
    *(short8*)&Bt[tid][0]  = *(const short8*)(wsrc);
    *(short8*)&Bt[tid][8]  = *(const short8*)(wsrc + 8);
    *(short8*)&Bt[tid][16] = *(const short8*)(wsrc + 16);
    *(short8*)&Bt[tid][24] = *(const short8*)(wsrc + 24);
    __syncthreads();
    short8 af[4], bv[4];
#pragma unroll
    for (int mi = 0; mi < 4; ++mi) af[mi] = *(short8*)&A[mi * 16 + lrow][lk8];
#pragma unroll
    for (int ni = 0; ni < 4; ++ni) bv[ni] = *(short8*)&Bt[nb + ni * 16 + lrow][lk8];
#pragma unroll
    for (int mi = 0; mi < 4; ++mi)
#pragma unroll
      for (int ni = 0; ni < 4; ++ni)
        acc[mi][ni] = mfma16(af[mi], bv[ni], acc[mi][ni]);
    __syncthreads();
  }
#pragma unroll
  for (int ni = 0; ni < 4; ++ni) {
    const int col = nb + ni * 16 + lrow;
    const float bias = b1[col];
#pragma unroll
    for (int mi = 0; mi < 4; ++mi)
#pragma unroll
      for (int j = 0; j < 4; ++j)
        Hh[mi * 16 + rq + j][col] = (short)f2bu(fmaxf(acc[mi][ni][j] + bias, 0.f));
  }

  // layer 2 (K=256) -> back into Hh
#pragma unroll
  for (int mi = 0; mi < 4; ++mi)
#pragma unroll
    for (int ni = 0; ni < 4; ++ni) acc[mi][ni] = fz;
  for (int ks = 0; ks < 8; ++ks) {
    const short* wsrc = w2t + tid * 256 + (ks << 5);
    *(short8*)&Bt[tid][0]  = *(const short8*)(wsrc);
    *(short8*)&Bt[tid][8]  = *(const short8*)(wsrc + 8);
    *(short8*)&Bt[tid][16] = *(const short8*)(wsrc + 16);
    *(short8*)&Bt[tid][24] = *(const short8*)(wsrc + 24);
    __syncthreads();
    short8 af[4], bv[4];
#pragma unroll
    for (int mi = 0; mi < 4; ++mi) af[mi] = *(short8*)&Hh[mi * 16 + lrow][(ks << 5) + lk8];
#pragma unroll
    for (int ni = 0; ni < 4; ++ni) bv[ni] = *(short8*)&Bt[nb + ni * 16 + lrow][lk8];
#pragma unroll
    for (int mi = 0; mi < 4; ++mi)
#pragma unroll
      for (int ni = 0; ni < 4; ++ni)
        acc[mi][ni] = mfma16(af[mi], bv[ni], acc[mi][ni]);
    __syncthreads();
  }
#pragma unroll
  for (int ni = 0; ni < 4; ++ni) {
    const int col = nb + ni * 16 + lrow;
    const float bias = b2[col];
#pragma unroll
    for (int mi = 0; mi < 4; ++mi)
#pragma unroll
      for (int j = 0; j < 4; ++j)
        Hh[mi * 16 + rq + j][col] = (short)f2bu(fmaxf(acc[mi][ni][j] + bias, 0.f));
  }
  __syncthreads();

  // layer 3 (K=256) -> f32 out
#pragma unroll
  for (int mi = 0; mi < 4; ++mi)
#pragma unroll
    for (int ni = 0; ni < 4; ++ni) acc[mi][ni] = fz;
  for (int ks = 0; ks < 8; ++ks) {
    const short* wsrc = w3t + tid * 256 + (ks << 5);
    *(short8*)&Bt[tid][0]  = *(const short8*)(wsrc);
    *(short8*)&Bt[tid][8]  = *(const short8*)(wsrc + 8);
    *(short8*)&Bt[tid][16] = *(const short8*)(wsrc + 16);
    *(short8*)&Bt[tid][24] = *(const short8*)(wsrc + 24);
    __syncthreads();
    short8 af[4], bv[4];
#pragma unroll
    for (int mi = 0; mi < 4; ++mi) af[mi] = *(short8*)&Hh[mi * 16 + lrow][(ks << 5) + lk8];
#pragma unroll
    for (int ni = 0; ni < 4; ++ni) bv[ni] = *(short8*)&Bt[nb + ni * 16 + lrow][lk8];
#pragma unroll
    for (int mi = 0; mi < 4; ++mi)
#pragma unroll
      for (int ni = 0; ni < 4; ++ni)
        acc[mi][ni] = mfma16(af[mi], bv[ni], acc[mi][ni]);
    __syncthreads();
  }
#pragma unroll
  for (int ni = 0; ni < 4; ++ni) {
    const int col = nb + ni * 16 + lrow;
    const float bias = b3[col];
#pragma unroll
    for (int mi = 0; mi < 4; ++mi)
#pragma unroll
      for (int j = 0; j < 4; ++j) {
        const int row = mi * 16 + rq + j;
        out[(size_t)(m0 + row) * 256 + col] = fmaxf(acc[mi][ni][j] + bias, 0.f);
      }
  }
}

// ---------------- head MLP (192->96 relu ->12) + masked softmax + weighted sum over 12 rows
__global__ __launch_bounds__(64) void k_head(
    const float* __restrict__ miu_in,   // [G][192]
    const int* __restrict__ mask_src, const int mstride,
    const short* __restrict__ src,      // [G*12][256] bf16
    const float* __restrict__ w1, const float* __restrict__ b1,
    const float* __restrict__ w2, const float* __restrict__ b2,
    short* __restrict__ outp)           // [G][256] bf16
{
  const int g = blockIdx.x;
  const int lane = threadIdx.x;
  __shared__ float in_s[192];
  __shared__ float h1[96];
  __shared__ float wgt[12];

  for (int i = lane; i < 192; i += 64) in_s[i] = miu_in[(size_t)g * 192 + i];
  __syncthreads();
  for (int j = lane; j < 96; j += 64) {
    float s = b1[j];
    for (int k = 0; k < 192; ++k) s += in_s[k] * w1[k * 96 + j];
    h1[j] = fmaxf(s, 0.f);
  }
  __syncthreads();
  if (lane < 12) {
    float s = b2[lane];
    for (int k = 0; k < 96; ++k) s += h1[k] * w2[k * 12 + lane];
    int mi = mask_src[(g * 12 + lane) * mstride];
    wgt[lane] = (mi > 0) ? expf(s) : 0.f;
  }
  __syncthreads();
  float tot = 1e-10f;
#pragma unroll
  for (int m = 0; m < 12; ++m) tot += wgt[m];
  const float inv = 1.f / tot;

  const int d0 = lane * 4;
  float o0 = 0.f, o1 = 0.f, o2 = 0.f, o3 = 0.f;
#pragma unroll
  for (int m = 0; m < 12; ++m) {
    const float wm = wgt[m] * inv;
    short4v x = *(const short4v*)(src + (((size_t)g * 12 + m) << 8) + d0);
    o0 += wm * b2f((unsigned short)x[0]);
    o1 += wm * b2f((unsigned short)x[1]);
    o2 += wm * b2f((unsigned short)x[2]);
    o3 += wm * b2f((unsigned short)x[3]);
  }
  short4v ov;
  ov[0] = (short)f2bu(o0); ov[1] = (short)f2bu(o1);
  ov[2] = (short)f2bu(o2); ov[3] = (short)f2bu(o3);
  *(short4v*)(outp + ((size_t)g << 8) + d0) = ov;
}

// =====================================================================
extern "C" void kernel_launch(void* const* d_in, const int* in_sizes, int n_in,
                              void* d_out, int out_size, void* d_ws, size_t ws_size,
                              hipStream_t stream)
{
  (void)in_sizes; (void)n_in; (void)out_size; (void)ws_size;

  const int*   iids = (const int*)d_in[0];
  const int*   iup  = (const int*)d_in[1];
  const int*   iip  = (const int*)d_in[2];
  const int*   iiup = (const int*)d_in[3];
  const float* user_table = (const float*)d_in[4];
  const float* item_table = (const float*)d_in[5];
  const float* rate_table = (const float*)d_in[6];
  const float* g_u_w1 = (const float*)d_in[7];   const float* g_u_b1 = (const float*)d_in[8];
  const float* g_u_w2 = (const float*)d_in[9];   const float* g_u_b2 = (const float*)d_in[10];
  const float* attu_w1 = (const float*)d_in[11]; const float* attu_b1 = (const float*)d_in[12];
  const float* attu_w2 = (const float*)d_in[13]; const float* attu_b2 = (const float*)d_in[14];
  const float* headu_w1 = (const float*)d_in[15]; const float* headu_b1 = (const float*)d_in[16];
  const float* headu_w2 = (const float*)d_in[17]; const float* headu_b2 = (const float*)d_in[18];
  const float* aggi_w = (const float*)d_in[19];  const float* aggi_b = (const float*)d_in[20];
  const float* attii_w1 = (const float*)d_in[21]; const float* attii_b1 = (const float*)d_in[22];
  const float* attii_w2 = (const float*)d_in[23]; const float* attii_b2 = (const float*)d_in[24];
  const float* headii_w1 = (const float*)d_in[25]; const float* headii_b1 = (const float*)d_in[26];
  const float* headii_w2 = (const float*)d_in[27]; const float* headii_b2 = (const float*)d_in[28];
  const float* aggii_w = (const float*)d_in[29]; const float* aggii_b = (const float*)d_in[30];
  const float* comb_w1 = (const float*)d_in[31]; const float* comb_b1 = (const float*)d_in[32];
  const float* comb_w2 = (const float*)d_in[33]; const float* comb_b2 = (const float*)d_in[34];
  const float* comb_w3 = (const float*)d_in[35]; const float* comb_b3 = (const float*)d_in[36];

  char* wsp = (char*)d_ws;
  size_t off = 0;
  auto alloc = [&](size_t bytes) -> void* {
    void* p = wsp + off;
    off += (bytes + 255) & ~(size_t)255;
    return p;
  };
  short* wt_gu1    = (short*)alloc((size_t)512 * 256 * 2);
  short* wt_gu2    = (short*)alloc((size_t)256 * 256 * 2);
  short* wt_attu1  = (short*)alloc((size_t)512 * 256 * 2);
  short* wt_attu2  = (short*)alloc((size_t)256 * 16 * 2);
  short* wt_aggi   = (short*)alloc((size_t)256 * 256 * 2);
  short* wt_attii1 = (short*)alloc((size_t)512 * 256 * 2);
  short* wt_attii2 = (short*)alloc((size_t)256 * 16 * 2);
  short* wt_aggii  = (short*)alloc((size_t)256 * 256 * 2);
  short* wt_comb1  = (short*)alloc((size_t)512 * 256 * 2);
  short* wt_comb2  = (short*)alloc((size_t)256 * 256 * 2);
  short* wt_comb3  = (short*)alloc((size_t)256 * 256 * 2);

  const int M2 = 2048 * 12 * 12;   // 294912
  const int M1 = 2048 * 12;        // 24576

  short* X      = (short*)alloc((size_t)M2 * 256 * 2);
  short* FJT    = (short*)alloc((size_t)M1 * 256 * 2);
  float* MIU2   = (float*)alloc((size_t)M2 * 16 * 4);
  float* MIU1   = (float*)alloc((size_t)M1 * 16 * 4);
  float* KAP    = (float*)alloc((size_t)M1 * 16 * 4);
  short* HPRE2  = (short*)alloc((size_t)M1 * 256 * 2);
  short* HOU    = (short*)alloc((size_t)M1 * 256 * 2);
  short* HPREJV = (short*)alloc((size_t)2048 * 256 * 2);
  short* HPRE1  = (short*)alloc((size_t)2048 * 256 * 2);
  short* HJU    = (short*)alloc((size_t)2048 * 256 * 2);
  short* HJV    = (short*)alloc((size_t)2048 * 256 * 2);

  auto wtl = [&](const float* w, short* dst, int K, int N) {
    int total = K * N;
    k_wt<<<(total + 255) / 256, 256, 0, stream>>>(w, dst, K, N);
  };
  wtl(g_u_w1, wt_gu1, 512, 256);
  wtl(g_u_w2, wt_gu2, 256, 256);
  wtl(attu_w1, wt_attu1, 512, 256);
  wtl(attu_w2, wt_attu2, 256, 16);
  wtl(aggi_w, wt_aggi, 256, 256);
  wtl(attii_w1, wt_attii1, 512, 256);
  wtl(attii_w2, wt_attii2, 256, 16);
  wtl(aggii_w, wt_aggii, 256, 256);
  wtl(comb_w1, wt_comb1, 512, 256);
  wtl(comb_w2, wt_comb2, 256, 256);
  wtl(comb_w3, wt_comb3, 256, 256);

  // part-2 inner (dominant) and part-1 g_u MLP
  k_mlp2<<<M2 / 64, 256, 0, stream>>>(iiup, item_table, rate_table,
                                      wt_gu1, g_u_b1, wt_gu2, g_u_b2, X);
  k_mlp2<<<M1 / 64, 256, 0, stream>>>(iup, user_table, rate_table,
                                      wt_gu1, g_u_b1, wt_gu2, g_u_b2, FJT);
  // attention scores
  k_att<2><<<M2 / 64, 256, 0, stream>>>(X, item_table, iids, iup, iip, iiup,
                                        wt_attu1, attu_b1, wt_attu2, attu_b2, MIU2);
  k_att<1><<<M1 / 64, 256, 0, stream>>>(FJT, item_table, iids, iup, iip, iiup,
                                        wt_attu1, attu_b1, wt_attu2, attu_b2, MIU1);
  // head + softmax + weighted sum (part-2 inner)
  k_head<<<M1, 64, 0, stream>>>(MIU2, iiup, 2, X,
                                headu_w1, headu_b1, headu_w2, headu_b2, HPRE2);
  // h_oU = relu(HPRE2 @ aggi + b)
  k_gemm1<<<M1 / 64, 256, 0, stream>>>(HPRE2, wt_aggi, aggi_b, HOU);
  // kappa scores
  k_att<3><<<M1 / 64, 256, 0, stream>>>(HOU, item_table, iids, iup, iip, iiup,
                                        wt_attii1, attii_b1, wt_attii2, attii_b2, KAP);
  // kappa head + weighted sum over n
  k_head<<<2048, 64, 0, stream>>>(KAP, iip, 1, HOU,
                                  headii_w1, headii_b1, headii_w2, headii_b2, HPREJV);
  // part-1 head + weighted sum over n
  k_head<<<2048, 64, 0, stream>>>(MIU1, iup, 2, FJT,
                                  headu_w1, headu_b1, headu_w2, headu_b2, HPRE1);
  // h_jU, h_jV
  k_gemm1<<<2048 / 64, 256, 0, stream>>>(HPRE1, wt_aggi, aggi_b, HJU);
  k_gemm1<<<2048 / 64, 256, 0, stream>>>(HPREJV, wt_aggii, aggii_b, HJV);
  // final comb MLP -> d_out (f32)
  k_comb<<<2048 / 64, 256, 0, stream>>>(HJU, HJV, wt_comb1, comb_b1,
                                        wt_comb2, comb_b2, wt_comb3, comb_b3,
                                        (float*)d_out);
}

// Round 2
// 665.816 us; speedup vs baseline: 1.2525x; 1.2525x over previous
//
#include <hip/hip_runtime.h>
#include <cstdint>
#include <cstddef>

typedef short short8 __attribute__((ext_vector_type(8)));
typedef short short4v __attribute__((ext_vector_type(4)));
typedef float f32x4 __attribute__((ext_vector_type(4)));
typedef __bf16 bf16x8 __attribute__((ext_vector_type(8)));

__device__ __forceinline__ unsigned short f2bu(float f) {
  union { float f; unsigned u; } v; v.f = f;
  unsigned r = v.u + 0x7FFFu + ((v.u >> 16) & 1u);
  return (unsigned short)(r >> 16);
}
__device__ __forceinline__ float b2f(unsigned short h) {
  union { unsigned u; float f; } v; v.u = ((unsigned)h) << 16;
  return v.f;
}

__device__ __forceinline__ f32x4 mfma16(short8 a, short8 b, f32x4 c) {
  return __builtin_amdgcn_mfma_f32_16x16x32_bf16(
      __builtin_bit_cast(bf16x8, a), __builtin_bit_cast(bf16x8, b), c, 0, 0, 0);
}

// async global->LDS, 16B per lane. dest = wave-uniform base (+ lane*16 by HW).
__device__ __forceinline__ void gl16(const void* g, void* l) {
  __builtin_amdgcn_global_load_lds(
      (const __attribute__((address_space(1))) unsigned int*)g,
      (__attribute__((address_space(3))) unsigned int*)l, 16, 0, 0);
}

// ---------------- f32 -> bf16 table convert (8/thread) ----------------
__global__ void k_cvt(const float* __restrict__ in, short* __restrict__ o, int ntot) {
  int i = (blockIdx.x * 256 + threadIdx.x) * 8;
  if (i >= ntot) return;
  float4 a = *(const float4*)(in + i);
  float4 b = *(const float4*)(in + i + 4);
  short8 v;
  v[0] = (short)f2bu(a.x); v[1] = (short)f2bu(a.y);
  v[2] = (short)f2bu(a.z); v[3] = (short)f2bu(a.w);
  v[4] = (short)f2bu(b.x); v[5] = (short)f2bu(b.y);
  v[6] = (short)f2bu(b.z); v[7] = (short)f2bu(b.w);
  *(short8*)(o + i) = v;
}

// ---------------- old-layout weight transpose: wt[n*K+k] = w[k*N+n] -------
__global__ void k_wt(const float* __restrict__ w, short* __restrict__ wt, int K, int N) {
  int t = blockIdx.x * 256 + threadIdx.x;
  if (t >= K * N) return;
  int n = t / K;
  int k = t - n * K;
  wt[t] = (short)f2bu(w[(size_t)k * N + n]);
}

// ---------------- swizzled-slab weight layout for global_load_lds ---------
// slab ks (32 k's): physical quantum P (16B) holds B[n=P>>2][k=ks*32+kq*8..+7]
// with kq = ((P&3) - (n>>1)) & 3  (=> frag reads are <=2-way bank conflicts)
__global__ void k_wgl(const float* __restrict__ w, short* __restrict__ o, int K, int N) {
  int t = blockIdx.x * 256 + threadIdx.x;
  if (t >= K * N) return;
  int ks = t / (N * 32);
  int rem = t - ks * (N * 32);
  int P = rem >> 3, j = rem & 7;
  int n = P >> 2;
  int kq = ((P & 3) - (n >> 1)) & 3;
  int k = ks * 32 + kq * 8 + j;
  o[t] = (short)f2bu(w[(size_t)k * N + n]);
}

// ---------------- fused g_u(512->256->256) + attu(512->256->16) ----------
// 64 rows/block, 256 thr. Tables pre-converted bf16; staging via global_load_lds.
// Swapped MFMA operands: lane holds 4 consecutive n for fixed m -> b64 writes.
__global__ __launch_bounds__(256, 3) void k_fused(
    const int* __restrict__ idx_pairs,   // [M][2] gather ids (emb, rate)
    const int* __restrict__ qidx_arr,    // [M/12] item id for q
    const short* __restrict__ tab0,      // bf16 emb table (user or item)
    const short* __restrict__ tab1,      // bf16 rate table
    const short* __restrict__ itembf,    // bf16 item table (for q)
    const short* __restrict__ zp,        // 512B zero page
    const short* __restrict__ ws1, const float* __restrict__ b1,
    const short* __restrict__ ws2, const float* __restrict__ b2,
    const short* __restrict__ aw1, const float* __restrict__ ab1,
    const short* __restrict__ aw2t, const float* __restrict__ ab2,
    short* __restrict__ Xout, float* __restrict__ miu_out)
{
  __shared__ __align__(16) short smem[27136]; // 54272 B -> 3 blocks/CU
  short* sA = smem;          // 2048 shorts (64 rows x 4 quanta)
  short* sB = smem + 2048;   // 8192 shorts (256 n x 4 quanta)
  short* sH = smem + 10240;  // 16896 = 64 x 264

  const int tid = threadIdx.x;
  const int lane = tid & 63;
  const int wave = tid >> 6;
  const int m0 = (int)blockIdx.x << 6;
  const int l15 = lane & 15;
  const int lq = lane >> 4;
  const int nb = wave << 6;

  // per-thread A-stage source (thread t fills physical quantum t)
  const int an = tid >> 2;
  const int kqA = ((tid & 3) - (an >> 1)) & 3;
  const int r = m0 + an;
  const int i0 = idx_pairs[2 * r];
  const int i1 = idx_pairs[2 * r + 1];
  const int qi = qidx_arr[r / 12];
  const short* a0 = tab0 + (size_t)i0 * 256 + kqA * 8;
  const short* a1 = tab1 + (size_t)i1 * 256 + kqA * 8;
  const short* aq = ((i0 > 0) ? (itembf + (size_t)qi * 256) : zp) + kqA * 8;
  short* dstA = sA + wave * 512;   // wave-uniform
  short* dstB = sB + wave * 2048;  // wave-uniform (4 chunks of 512)

  // frag LDS offsets (shorts), k-step invariant
  int pA[4], pB[4];
#pragma unroll
  for (int i = 0; i < 4; ++i) {
    int m = i * 16 + l15;
    pA[i] = (m * 4 + ((lq + (m >> 1)) & 3)) * 8;
    int n = nb + i * 16 + l15;
    pB[i] = (n * 4 + ((lq + (n >> 1)) & 3)) * 8;
  }
  const int hOff = lq * 8;

  const f32x4 fz = {0.f, 0.f, 0.f, 0.f};
  f32x4 acc[4][4];
#pragma unroll
  for (int ni = 0; ni < 4; ++ni)
#pragma unroll
    for (int mi = 0; mi < 4; ++mi) acc[ni][mi] = fz;

  // ================= g_u layer 1 (K=512) =================
  for (int ks = 0; ks < 16; ++ks) {
    gl16((ks < 8) ? (a0 + ks * 32) : (a1 + (ks - 8) * 32), dstA);
    const short* bs = ws1 + ks * 8192 + wave * 2048 + lane * 8;
#pragma unroll
    for (int i = 0; i < 4; ++i) gl16(bs + i * 512, dstB + i * 512);
    __syncthreads();
    short8 wf[4], xf[4];
#pragma unroll
    for (int i = 0; i < 4; ++i) {
      wf[i] = *(short8*)(sB + pB[i]);
      xf[i] = *(short8*)(sA + pA[i]);
    }
#pragma unroll
    for (int ni = 0; ni < 4; ++ni)
#pragma unroll
      for (int mi = 0; mi < 4; ++mi)
        acc[ni][mi] = mfma16(wf[ni], xf[mi], acc[ni][mi]);
    __syncthreads();
  }
  // hidden = relu(+b1) -> sH  (lane: 4 consecutive n at fixed m -> b64)
#pragma unroll
  for (int ni = 0; ni < 4; ++ni) {
    const int nbase = nb + ni * 16 + lq * 4;
    float4 bb = *(const float4*)(b1 + nbase);
#pragma unroll
    for (int mi = 0; mi < 4; ++mi) {
      const int m = mi * 16 + l15;
      short4v hv;
      hv[0] = (short)f2bu(fmaxf(acc[ni][mi][0] + bb.x, 0.f));
      hv[1] = (short)f2bu(fmaxf(acc[ni][mi][1] + bb.y, 0.f));
      hv[2] = (short)f2bu(fmaxf(acc[ni][mi][2] + bb.z, 0.f));
      hv[3] = (short)f2bu(fmaxf(acc[ni][mi][3] + bb.w, 0.f));
      *(short4v*)(sH + m * 264 + nbase) = hv;
    }
  }
  __syncthreads();

  // ================= g_u layer 2 (K=256, A from sH) =================
#pragma unroll
  for (int ni = 0; ni < 4; ++ni)
#pragma unroll
    for (int mi = 0; mi < 4; ++mi) acc[ni][mi] = fz;
  for (int ks = 0; ks < 8; ++ks) {
    const short* bs = ws2 + ks * 8192 + wave * 2048 + lane * 8;
#pragma unroll
    for (int i = 0; i < 4; ++i) gl16(bs + i * 512, dstB + i * 512);
    __syncthreads();
    short8 wf[4], hf[4];
#pragma unroll
    for (int i = 0; i < 4; ++i) {
      wf[i] = *(short8*)(sB + pB[i]);
      hf[i] = *(short8*)(sH + (i * 16 + l15) * 264 + ks * 32 + hOff);
    }
#pragma unroll
    for (int ni = 0; ni < 4; ++ni)
#pragma unroll
      for (int mi = 0; mi < 4; ++mi)
        acc[ni][mi] = mfma16(wf[ni], hf[mi], acc[ni][mi]);
    __syncthreads();
  }
  // f_jt = acc + b2 (no relu) -> X global + sH (for attn L1)
#pragma unroll
  for (int ni = 0; ni < 4; ++ni) {
    const int nbase = nb + ni * 16 + lq * 4;
    float4 bb = *(const float4*)(b2 + nbase);
#pragma unroll
    for (int mi = 0; mi < 4; ++mi) {
      const int m = mi * 16 + l15;
      short4v hv;
      hv[0] = (short)f2bu(acc[ni][mi][0] + bb.x);
      hv[1] = (short)f2bu(acc[ni][mi][1] + bb.y);
      hv[2] = (short)f2bu(acc[ni][mi][2] + bb.z);
      hv[3] = (short)f2bu(acc[ni][mi][3] + bb.w);
      *(short4v*)(sH + m * 264 + nbase) = hv;
      *(short4v*)(Xout + (size_t)(m0 + m) * 256 + nbase) = hv;
    }
  }
  __syncthreads();

  // ================= attn layer 1 (K=512: sH | staged Q) =================
#pragma unroll
  for (int ni = 0; ni < 4; ++ni)
#pragma unroll
    for (int mi = 0; mi < 4; ++mi) acc[ni][mi] = fz;
  for (int ks = 0; ks < 16; ++ks) {
    if (ks >= 8) gl16(aq + (ks - 8) * 32, dstA);
    const short* bs = aw1 + ks * 8192 + wave * 2048 + lane * 8;
#pragma unroll
    for (int i = 0; i < 4; ++i) gl16(bs + i * 512, dstB + i * 512);
    __syncthreads();
    short8 wf[4], xf[4];
#pragma unroll
    for (int i = 0; i < 4; ++i) wf[i] = *(short8*)(sB + pB[i]);
    if (ks < 8) {
#pragma unroll
      for (int i = 0; i < 4; ++i)
        xf[i] = *(short8*)(sH + (i * 16 + l15) * 264 + ks * 32 + hOff);
    } else {
#pragma unroll
      for (int i = 0; i < 4; ++i) xf[i] = *(short8*)(sA + pA[i]);
    }
#pragma unroll
    for (int ni = 0; ni < 4; ++ni)
#pragma unroll
      for (int mi = 0; mi < 4; ++mi)
        acc[ni][mi] = mfma16(wf[ni], xf[mi], acc[ni][mi]);
    __syncthreads();
  }
  // attn hidden = relu(+ab1) -> sH (overwrite)
#pragma unroll
  for (int ni = 0; ni < 4; ++ni) {
    const int nbase = nb + ni * 16 + lq * 4;
    float4 bb = *(const float4*)(ab1 + nbase);
#pragma unroll
    for (int mi = 0; mi < 4; ++mi) {
      const int m = mi * 16 + l15;
      short4v hv;
      hv[0] = (short)f2bu(fmaxf(acc[ni][mi][0] + bb.x, 0.f));
      hv[1] = (short)f2bu(fmaxf(acc[ni][mi][1] + bb.y, 0.f));
      hv[2] = (short)f2bu(fmaxf(acc[ni][mi][2] + bb.z, 0.f));
      hv[3] = (short)f2bu(fmaxf(acc[ni][mi][3] + bb.w, 0.f));
      *(short4v*)(sH + m * 264 + nbase) = hv;
    }
  }
  __syncthreads();

  // ================= attn layer 2 (256 -> 16), per-wave 16 rows ==========
  {
    short* W2s = smem; // [16][264] aliases sA/sB
    const int rw = tid & 15, seg = (tid >> 4) << 4;
    *(short8*)(W2s + rw * 264 + seg)     = *(const short8*)(aw2t + rw * 256 + seg);
    *(short8*)(W2s + rw * 264 + seg + 8) = *(const short8*)(aw2t + rw * 256 + seg + 8);
  }
  __syncthreads();
  f32x4 a2 = fz;
#pragma unroll
  for (int ks = 0; ks < 8; ++ks) {
    short8 af = *(short8*)(sH + (wave * 16 + l15) * 264 + ks * 32 + hOff);
    short8 bv = *(short8*)(smem + l15 * 264 + ks * 32 + hOff);
    a2 = mfma16(af, bv, a2);
  }
  const float bias = ab2[l15];
#pragma unroll
  for (int j = 0; j < 4; ++j)
    miu_out[(size_t)(m0 + wave * 16 + lq * 4 + j) * 16 + l15] = a2[j] + bias;
}

// ---------------- kappa scores: concat(HOU[r], item_table[iip[r]]) -> 16 --
__global__ __launch_bounds__(256, 2) void k_att3(
    const short* __restrict__ first,
    const float* __restrict__ item_table,
    const int* __restrict__ i_item_pad,
    const short* __restrict__ w1t, const float* __restrict__ b1,
    const short* __restrict__ w2t, const float* __restrict__ b2,
    float* __restrict__ miu_out)
{
  __shared__ __align__(16) short smem[29696];
  short (*A)[40]   = (short(*)[40])smem;
  short (*Bt)[40]  = (short(*)[40])(smem + 2560);
  short (*W2)[264] = (short(*)[264])smem;
  short (*Hh)[264] = (short(*)[264])(smem + 12800);

  const int tid  = threadIdx.x;
  const int lane = tid & 63;
  const int wave = tid >> 6;
  const int m0   = blockIdx.x << 6;
  const int arow = tid >> 2;
  const int acol8 = (tid & 3) << 3;
  const int lrow = lane & 15;
  const int lk8  = (lane >> 4) << 3;
  const int rq   = (lane >> 4) << 2;
  const int nb   = wave << 6;

  const int r = m0 + arow;
  const int sidx = i_item_pad[r];
  const float* src1 = item_table + (size_t)sidx * 256;
  const short* fsrc = first + (size_t)r * 256;

  const f32x4 fz = {0.f, 0.f, 0.f, 0.f};
  f32x4 acc[4][4];
#pragma unroll
  for (int mi = 0; mi < 4; ++mi)
#pragma unroll
    for (int ni = 0; ni < 4; ++ni) acc[mi][ni] = fz;

  for (int ks = 0; ks < 16; ++ks) {
    const int kg = (ks << 5) + acol8;
    short8 av;
    if (kg < 256) {
      av = *(const short8*)(fsrc + kg);
    } else {
      float4 v0 = *(const float4*)(src1 + (kg - 256));
      float4 v1 = *(const float4*)(src1 + (kg - 252));
      av[0] = (short)f2bu(v0.x); av[1] = (short)f2bu(v0.y);
      av[2] = (short)f2bu(v0.z); av[3] = (short)f2bu(v0.w);
      av[4] = (short)f2bu(v1.x); av[5] = (short)f2bu(v1.y);
      av[6] = (short)f2bu(v1.z); av[7] = (short)f2bu(v1.w);
    }
    *(short8*)&A[arow][acol8] = av;
    const short* wsrc = w1t + tid * 512 + (ks << 5);
    *(short8*)&Bt[tid][0]  = *(const short8*)(wsrc);
    *(short8*)&Bt[tid][8]  = *(const short8*)(wsrc + 8);
    *(short8*)&Bt[tid][16] = *(const short8*)(wsrc + 16);
    *(short8*)&Bt[tid][24] = *(const short8*)(wsrc + 24);
    __syncthreads();
    short8 af[4], bv[4];
#pragma unroll
    for (int mi = 0; mi < 4; ++mi) af[mi] = *(short8*)&A[mi * 16 + lrow][lk8];
#pragma unroll
    for (int ni = 0; ni < 4; ++ni) bv[ni] = *(short8*)&Bt[nb + ni * 16 + lrow][lk8];
#pragma unroll
    for (int mi = 0; mi < 4; ++mi)
#pragma unroll
      for (int ni = 0; ni < 4; ++ni)
        acc[mi][ni] = mfma16(af[mi], bv[ni], acc[mi][ni]);
    __syncthreads();
  }

#pragma unroll
  for (int ni = 0; ni < 4; ++ni) {
    const int col = nb + ni * 16 + lrow;
    const float bias = b1[col];
#pragma unroll
    for (int mi = 0; mi < 4; ++mi)
#pragma unroll
      for (int j = 0; j < 4; ++j) {
        const int row = mi * 16 + rq + j;
        Hh[row][col] = (short)f2bu(fmaxf(acc[mi][ni][j] + bias, 0.f));
      }
  }
  {
    const int rw  = tid & 15;
    const int seg = (tid >> 4) << 4;
    const short* s = w2t + rw * 256 + seg;
    *(short8*)&W2[rw][seg]     = *(const short8*)(s);
    *(short8*)&W2[rw][seg + 8] = *(const short8*)(s + 8);
  }
  __syncthreads();

  f32x4 acc2 = fz;
#pragma unroll
  for (int ks = 0; ks < 8; ++ks) {
    short8 af = *(short8*)&Hh[(wave << 4) + lrow][(ks << 5) + lk8];
    short8 bv = *(short8*)&W2[lrow][(ks << 5) + lk8];
    acc2 = mfma16(af, bv, acc2);
  }
  const float bias = b2[lrow];
#pragma unroll
  for (int j = 0; j < 4; ++j) {
    const int row = (wave << 4) + rq + j;
    miu_out[(size_t)(m0 + row) * 16 + lrow] = acc2[j] + bias;
  }
}

// ---------------- single-layer GEMM 256->256 + bias + relu ----------------
__global__ __launch_bounds__(256, 2) void k_gemm1(
    const short* __restrict__ Abf, const short* __restrict__ wt,
    const float* __restrict__ bias, short* __restrict__ out)
{
  __shared__ __align__(16) short smem[12800];
  short (*A)[40]  = (short(*)[40])smem;
  short (*Bt)[40] = (short(*)[40])(smem + 2560);

  const int tid  = threadIdx.x;
  const int lane = tid & 63;
  const int wave = tid >> 6;
  const int m0   = blockIdx.x << 6;
  const int arow = tid >> 2;
  const int acol8 = (tid & 3) << 3;
  const int lrow = lane & 15;
  const int lk8  = (lane >> 4) << 3;
  const int rq   = (lane >> 4) << 2;
  const int nb   = wave << 6;
  const int r = m0 + arow;

  const f32x4 fz = {0.f, 0.f, 0.f, 0.f};
  f32x4 acc[4][4];
#pragma unroll
  for (int mi = 0; mi < 4; ++mi)
#pragma unroll
    for (int ni = 0; ni < 4; ++ni) acc[mi][ni] = fz;

  for (int ks = 0; ks < 8; ++ks) {
    *(short8*)&A[arow][acol8] = *(const short8*)(Abf + (size_t)r * 256 + (ks << 5) + acol8);
    const short* wsrc = wt + tid * 256 + (ks << 5);
    *(short8*)&Bt[tid][0]  = *(const short8*)(wsrc);
    *(short8*)&Bt[tid][8]  = *(const short8*)(wsrc + 8);
    *(short8*)&Bt[tid][16] = *(const short8*)(wsrc + 16);
    *(short8*)&Bt[tid][24] = *(const short8*)(wsrc + 24);
    __syncthreads();
    short8 af[4], bv[4];
#pragma unroll
    for (int mi = 0; mi < 4; ++mi) af[mi] = *(short8*)&A[mi * 16 + lrow][lk8];
#pragma unroll
    for (int ni = 0; ni < 4; ++ni) bv[ni] = *(short8*)&Bt[nb + ni * 16 + lrow][lk8];
#pragma unroll
    for (int mi = 0; mi < 4; ++mi)
#pragma unroll
      for (int ni = 0; ni < 4; ++ni)
        acc[mi][ni] = mfma16(af[mi], bv[ni], acc[mi][ni]);
    __syncthreads();
  }

#pragma unroll
  for (int ni = 0; ni < 4; ++ni) {
    const int col = nb + ni * 16 + lrow;
    const float b = bias[col];
#pragma unroll
    for (int mi = 0; mi < 4; ++mi)
#pragma unroll
      for (int j = 0; j < 4; ++j) {
        const int row = mi * 16 + rq + j;
        out[(size_t)(m0 + row) * 256 + col] = (short)f2bu(fmaxf(acc[mi][ni][j] + b, 0.f));
      }
  }
}

// ---------------- fused 3-layer comb MLP --------------------------------
__global__ __launch_bounds__(256, 2) void k_comb(
    const short* __restrict__ hju, const short* __restrict__ hjv,
    const short* __restrict__ w1t, const float* __restrict__ b1,
    const short* __restrict__ w2t, const float* __restrict__ b2,
    const short* __restrict__ w3t, const float* __restrict__ b3,
    float* __restrict__ out)
{
  __shared__ __align__(16) short smem[29696];
  short (*A)[40]   = (short(*)[40])smem;
  short (*Bt)[40]  = (short(*)[40])(smem + 2560);
  short (*Hh)[264] = (short(*)[264])(smem + 12800);

  const int tid  = threadIdx.x;
  const int lane = tid & 63;
  const int wave = tid >> 6;
  const int m0   = blockIdx.x << 6;
  const int arow = tid >> 2;
  const int acol8 = (tid & 3) << 3;
  const int lrow = lane & 15;
  const int lk8  = (lane >> 4) << 3;
  const int rq   = (lane >> 4) << 2;
  const int nb   = wave << 6;
  const int r = m0 + arow;

  const f32x4 fz = {0.f, 0.f, 0.f, 0.f};
  f32x4 acc[4][4];
#pragma unroll
  for (int mi = 0; mi < 4; ++mi)
#pragma unroll
    for (int ni = 0; ni < 4; ++ni) acc[mi][ni] = fz;

  for (int ks = 0; ks < 16; ++ks) {
    const int kg = (ks << 5) + acol8;
    short8 av = (kg < 256) ? *(const short8*)(hju + (size_t)r * 256 + kg)
                           : *(const short8*)(hjv + (size_t)r * 256 + (kg - 256));
    *(short8*)&A[arow][acol8] = av;
    const short* wsrc = w1t + tid * 512 + (ks << 5);
    *(short8*)&Bt[tid][0]  = *(const short8*)(wsrc);
    *(short8*)&Bt[tid][8]  = *(const short8*)(wsrc + 8);
    *(short8*)&Bt[tid][16] = *(const short8*)(wsrc + 16);
    *(short8*)&Bt[tid][24] = *(const short8*)(wsrc + 24);
    __syncthreads();
    short8 af[4], bv[4];
#pragma unroll
    for (int mi = 0; mi < 4; ++mi) af[mi] = *(short8*)&A[mi * 16 + lrow][lk8];
#pragma unroll
    for (int ni = 0; ni < 4; ++ni) bv[ni] = *(short8*)&Bt[nb + ni * 16 + lrow][lk8];
#pragma unroll
    for (int mi = 0; mi < 4; ++mi)
#pragma unroll
      for (int ni = 0; ni < 4; ++ni)
        acc[mi][ni] = mfma16(af[mi], bv[ni], acc[mi][ni]);
    __syncthreads();
  }
#pragma unroll
  for (int ni = 0; ni < 4; ++ni) {
    const int col = nb + ni * 16 + lrow;
    const float bias = b1[col];
#pragma unroll
    for (int mi = 0; mi < 4; ++mi)
#pragma unroll
      for (int j = 0; j < 4; ++j)
        Hh[mi * 16 + rq + j][col] = (short)f2bu(fmaxf(acc[mi][ni][j] + bias, 0.f));
  }

#pragma unroll
  for (int mi = 0; mi < 4; ++mi)
#pragma unroll
    for (int ni = 0; ni < 4; ++ni) acc[mi][ni] = fz;
  for (int ks = 0; ks < 8; ++ks) {
    const short* wsrc = w2t + tid * 256 + (ks << 5);
    *(short8*)&Bt[tid][0]  = *(const short8*)(wsrc);
    *(short8*)&Bt[tid][8]  = *(const short8*)(wsrc + 8);
    *(short8*)&Bt[tid][16] = *(const short8*)(wsrc + 16);
    *(short8*)&Bt[tid][24] = *(const short8*)(wsrc + 24);
    __syncthreads();
    short8 af[4], bv[4];
#pragma unroll
    for (int mi = 0; mi < 4; ++mi) af[mi] = *(short8*)&Hh[mi * 16 + lrow][(ks << 5) + lk8];
#pragma unroll
    for (int ni = 0; ni < 4; ++ni) bv[ni] = *(short8*)&Bt[nb + ni * 16 + lrow][lk8];
#pragma unroll
    for (int mi = 0; mi < 4; ++mi)
#pragma unroll
      for (int ni = 0; ni < 4; ++ni)
        acc[mi][ni] = mfma16(af[mi], bv[ni], acc[mi][ni]);
    __syncthreads();
  }
#pragma unroll
  for (int ni = 0; ni < 4; ++ni) {
    const int col = nb + ni * 16 + lrow;
    const float bias = b2[col];
#pragma unroll
    for (int mi = 0; mi < 4; ++mi)
#pragma unroll
      for (int j = 0; j < 4; ++j)
        Hh[mi * 16 + rq + j][col] = (short)f2bu(fmaxf(acc[mi][ni][j] + bias, 0.f));
  }
  __syncthreads();

#pragma unroll
  for (int mi = 0; mi < 4; ++mi)
#pragma unroll
    for (int ni = 0; ni < 4; ++ni) acc[mi][ni] = fz;
  for (int ks = 0; ks < 8; ++ks) {
    const short* wsrc = w3t + tid * 256 + (ks << 5);
    *(short8*)&Bt[tid][0]  = *(const short8*)(wsrc);
    *(short8*)&Bt[tid][8]  = *(const short8*)(wsrc + 8);
    *(short8*)&Bt[tid][16] = *(const short8*)(wsrc + 16);
    *(short8*)&Bt[tid][24] = *(const short8*)(wsrc + 24);
    __syncthreads();
    short8 af[4], bv[4];
#pragma unroll
    for (int mi = 0; mi < 4; ++mi) af[mi] = *(short8*)&Hh[mi * 16 + lrow][(ks << 5) + lk8];
#pragma unroll
    for (int ni = 0; ni < 4; ++ni) bv[ni] = *(short8*)&Bt[nb + ni * 16 + lrow][lk8];
#pragma unroll
    for (int mi = 0; mi < 4; ++mi)
#pragma unroll
      for (int ni = 0; ni < 4; ++ni)
        acc[mi][ni] = mfma16(af[mi], bv[ni], acc[mi][ni]);
    __syncthreads();
  }
#pragma unroll
  for (int ni = 0; ni < 4; ++ni) {
    const int col = nb + ni * 16 + lrow;
    const float bias = b3[col];
#pragma unroll
    for (int mi = 0; mi < 4; ++mi)
#pragma unroll
      for (int j = 0; j < 4; ++j) {
        const int row = mi * 16 + rq + j;
        out[(size_t)(m0 + row) * 256 + col] = fmaxf(acc[mi][ni][j] + bias, 0.f);
      }
  }
}

// ---------------- head MLP + masked softmax + weighted sum ----------------
__global__ __launch_bounds__(64) void k_head(
    const float* __restrict__ miu_in,
    const int* __restrict__ mask_src, const int mstride,
    const short* __restrict__ src,
    const float* __restrict__ w1, const float* __restrict__ b1,
    const float* __restrict__ w2, const float* __restrict__ b2,
    short* __restrict__ outp)
{
  const int g = blockIdx.x;
  const int lane = threadIdx.x;
  __shared__ float in_s[192];
  __shared__ float h1[96];
  __shared__ float wgt[12];

  for (int i = lane; i < 192; i += 64) in_s[i] = miu_in[(size_t)g * 192 + i];
  __syncthreads();
  for (int j = lane; j < 96; j += 64) {
    float s = b1[j];
    for (int k = 0; k < 192; ++k) s += in_s[k] * w1[k * 96 + j];
    h1[j] = fmaxf(s, 0.f);
  }
  __syncthreads();
  if (lane < 12) {
    float s = b2[lane];
    for (int k = 0; k < 96; ++k) s += h1[k] * w2[k * 12 + lane];
    int mi = mask_src[(g * 12 + lane) * mstride];
    wgt[lane] = (mi > 0) ? expf(s) : 0.f;
  }
  __syncthreads();
  float tot = 1e-10f;
#pragma unroll
  for (int m = 0; m < 12; ++m) tot += wgt[m];
  const float inv = 1.f / tot;

  const int d0 = lane * 4;
  float o0 = 0.f, o1 = 0.f, o2 = 0.f, o3 = 0.f;
#pragma unroll
  for (int m = 0; m < 12; ++m) {
    const float wm = wgt[m] * inv;
    short4v x = *(const short4v*)(src + (((size_t)g * 12 + m) << 8) + d0);
    o0 += wm * b2f((unsigned short)x[0]);
    o1 += wm * b2f((unsigned short)x[1]);
    o2 += wm * b2f((unsigned short)x[2]);
    o3 += wm * b2f((unsigned short)x[3]);
  }
  short4v ov;
  ov[0] = (short)f2bu(o0); ov[1] = (short)f2bu(o1);
  ov[2] = (short)f2bu(o2); ov[3] = (short)f2bu(o3);
  *(short4v*)(outp + ((size_t)g << 8) + d0) = ov;
}

// =====================================================================
extern "C" void kernel_launch(void* const* d_in, const int* in_sizes, int n_in,
                              void* d_out, int out_size, void* d_ws, size_t ws_size,
                              hipStream_t stream)
{
  (void)in_sizes; (void)n_in; (void)out_size; (void)ws_size;

  const int*   iids = (const int*)d_in[0];
  const int*   iup  = (const int*)d_in[1];
  const int*   iip  = (const int*)d_in[2];
  const int*   iiup = (const int*)d_in[3];
  const float* user_table = (const float*)d_in[4];
  const float* item_table = (const float*)d_in[5];
  const float* rate_table = (const float*)d_in[6];
  const float* g_u_w1 = (const float*)d_in[7];   const float* g_u_b1 = (const float*)d_in[8];
  const float* g_u_w2 = (const float*)d_in[9];   const float* g_u_b2 = (const float*)d_in[10];
  const float* attu_w1 = (const float*)d_in[11]; const float* attu_b1 = (const float*)d_in[12];
  const float* attu_w2 = (const float*)d_in[13]; const float* attu_b2 = (const float*)d_in[14];
  const float* headu_w1 = (const float*)d_in[15]; const float* headu_b1 = (const float*)d_in[16];
  const float* headu_w2 = (const float*)d_in[17]; const float* headu_b2 = (const float*)d_in[18];
  const float* aggi_w = (const float*)d_in[19];  const float* aggi_b = (const float*)d_in[20];
  const float* attii_w1 = (const float*)d_in[21]; const float* attii_b1 = (const float*)d_in[22];
  const float* attii_w2 = (const float*)d_in[23]; const float* attii_b2 = (const float*)d_in[24];
  const float* headii_w1 = (const float*)d_in[25]; const float* headii_b1 = (const float*)d_in[26];
  const float* headii_w2 = (const float*)d_in[27]; const float* headii_b2 = (const float*)d_in[28];
  const float* aggii_w = (const float*)d_in[29]; const float* aggii_b = (const float*)d_in[30];
  const float* comb_w1 = (const float*)d_in[31]; const float* comb_b1 = (const float*)d_in[32];
  const float* comb_w2 = (const float*)d_in[33]; const float* comb_b2 = (const float*)d_in[34];
  const float* comb_w3 = (const float*)d_in[35]; const float* comb_b3 = (const float*)d_in[36];

  const int NUe = 100000 * 256, NIe = 100000 * 256, NRe = 6 * 256;
  char* wsp = (char*)d_ws;
  size_t off = 0;
  auto alloc = [&](size_t bytes) -> void* {
    void* p = wsp + off;
    off += (bytes + 255) & ~(size_t)255;
    return p;
  };
  short* user_bf = (short*)alloc((size_t)NUe * 2);
  short* item_bf = (short*)alloc((size_t)NIe * 2);
  short* rate_bf = (short*)alloc((size_t)NRe * 2);
  short* zp      = (short*)alloc(512);
  short* sl_gu1   = (short*)alloc((size_t)512 * 256 * 2);
  short* sl_gu2   = (short*)alloc((size_t)256 * 256 * 2);
  short* sl_attu1 = (short*)alloc((size_t)512 * 256 * 2);
  short* wt_attu2 = (short*)alloc((size_t)256 * 16 * 2);
  short* wt_aggi   = (short*)alloc((size_t)256 * 256 * 2);
  short* wt_attii1 = (short*)alloc((size_t)512 * 256 * 2);
  short* wt_attii2 = (short*)alloc((size_t)256 * 16 * 2);
  short* wt_aggii  = (short*)alloc((size_t)256 * 256 * 2);
  short* wt_comb1  = (short*)alloc((size_t)512 * 256 * 2);
  short* wt_comb2  = (short*)alloc((size_t)256 * 256 * 2);
  short* wt_comb3  = (short*)alloc((size_t)256 * 256 * 2);

  const int M2 = 2048 * 12 * 12;
  const int M1 = 2048 * 12;

  short* X      = (short*)alloc((size_t)M2 * 256 * 2);
  short* FJT    = (short*)alloc((size_t)M1 * 256 * 2);
  float* MIU2   = (float*)alloc((size_t)M2 * 16 * 4);
  float* MIU1   = (float*)alloc((size_t)M1 * 16 * 4);
  float* KAP    = (float*)alloc((size_t)M1 * 16 * 4);
  short* HPRE2  = (short*)alloc((size_t)M1 * 256 * 2);
  short* HOU    = (short*)alloc((size_t)M1 * 256 * 2);
  short* HPREJV = (short*)alloc((size_t)2048 * 256 * 2);
  short* HPRE1  = (short*)alloc((size_t)2048 * 256 * 2);
  short* HJU    = (short*)alloc((size_t)2048 * 256 * 2);
  short* HJV    = (short*)alloc((size_t)2048 * 256 * 2);

  hipMemsetAsync(zp, 0, 512, stream);
  k_cvt<<<NUe / 8 / 256, 256, 0, stream>>>(user_table, user_bf, NUe);
  k_cvt<<<NIe / 8 / 256, 256, 0, stream>>>(item_table, item_bf, NIe);
  k_cvt<<<1, 256, 0, stream>>>(rate_table, rate_bf, NRe);

  auto wgl = [&](const float* w, short* dst, int K, int N) {
    k_wgl<<<(K * N + 255) / 256, 256, 0, stream>>>(w, dst, K, N);
  };
  auto wtl = [&](const float* w, short* dst, int K, int N) {
    k_wt<<<(K * N + 255) / 256, 256, 0, stream>>>(w, dst, K, N);
  };
  wgl(g_u_w1, sl_gu1, 512, 256);
  wgl(g_u_w2, sl_gu2, 256, 256);
  wgl(attu_w1, sl_attu1, 512, 256);
  wtl(attu_w2, wt_attu2, 256, 16);
  wtl(aggi_w, wt_aggi, 256, 256);
  wtl(attii_w1, wt_attii1, 512, 256);
  wtl(attii_w2, wt_attii2, 256, 16);
  wtl(aggii_w, wt_aggii, 256, 256);
  wtl(comb_w1, wt_comb1, 512, 256);
  wtl(comb_w2, wt_comb2, 256, 256);
  wtl(comb_w3, wt_comb3, 256, 256);

  // fused g_u + attu : part-2 inner (dominant), then part-1
  k_fused<<<M2 / 64, 256, 0, stream>>>(iiup, iip, item_bf, rate_bf, item_bf, zp,
                                       sl_gu1, g_u_b1, sl_gu2, g_u_b2,
                                       sl_attu1, attu_b1, wt_attu2, attu_b2,
                                       X, MIU2);
  k_fused<<<M1 / 64, 256, 0, stream>>>(iup, iids, user_bf, rate_bf, item_bf, zp,
                                       sl_gu1, g_u_b1, sl_gu2, g_u_b2,
                                       sl_attu1, attu_b1, wt_attu2, attu_b2,
                                       FJT, MIU1);

  k_head<<<M1, 64, 0, stream>>>(MIU2, iiup, 2, X,
                                headu_w1, headu_b1, headu_w2, headu_b2, HPRE2);
  k_gemm1<<<M1 / 64, 256, 0, stream>>>(HPRE2, wt_aggi, aggi_b, HOU);
  k_att3<<<M1 / 64, 256, 0, stream>>>(HOU, item_table, iip,
                                      wt_attii1, attii_b1, wt_attii2, attii_b2, KAP);
  k_head<<<2048, 64, 0, stream>>>(KAP, iip, 1, HOU,
                                  headii_w1, headii_b1, headii_w2, headii_b2, HPREJV);
  k_head<<<2048, 64, 0, stream>>>(MIU1, iup, 2, FJT,
                                  headu_w1, headu_b1, headu_w2, headu_b2, HPRE1);
  k_gemm1<<<2048 / 64, 256, 0, stream>>>(HPRE1, wt_aggi, aggi_b, HJU);
  k_gemm1<<<2048 / 64, 256, 0, stream>>>(HPREJV, wt_aggii, aggii_b, HJV);
  k_comb<<<2048 / 64, 256, 0, stream>>>(HJU, HJV, wt_comb1, comb_b1,
                                        wt_comb2, comb_b2, wt_comb3, comb_b3,
                                        (float*)d_out);
}

// Round 3
// 640.211 us; speedup vs baseline: 1.3026x; 1.0400x over previous
//
#include <hip/hip_runtime.h>
#include <cstdint>
#include <cstddef>

typedef short short8 __attribute__((ext_vector_type(8)));
typedef short short4v __attribute__((ext_vector_type(4)));
typedef float f32x4 __attribute__((ext_vector_type(4)));
typedef __bf16 bf16x8 __attribute__((ext_vector_type(8)));

__device__ __forceinline__ unsigned short f2bu(float f) {
  union { float f; unsigned u; } v; v.f = f;
  unsigned r = v.u + 0x7FFFu + ((v.u >> 16) & 1u);
  return (unsigned short)(r >> 16);
}
__device__ __forceinline__ float b2f(unsigned short h) {
  union { unsigned u; float f; } v; v.u = ((unsigned)h) << 16;
  return v.f;
}

__device__ __forceinline__ f32x4 mfma16(short8 a, short8 b, f32x4 c) {
  return __builtin_amdgcn_mfma_f32_16x16x32_bf16(
      __builtin_bit_cast(bf16x8, a), __builtin_bit_cast(bf16x8, b), c, 0, 0, 0);
}

// ---------------- f32 -> bf16 table convert (8/thread) ----------------
__global__ void k_cvt(const float* __restrict__ in, short* __restrict__ o, int ntot) {
  int i = (blockIdx.x * 256 + threadIdx.x) * 8;
  if (i >= ntot) return;
  float4 a = *(const float4*)(in + i);
  float4 b = *(const float4*)(in + i + 4);
  short8 v;
  v[0] = (short)f2bu(a.x); v[1] = (short)f2bu(a.y);
  v[2] = (short)f2bu(a.z); v[3] = (short)f2bu(a.w);
  v[4] = (short)f2bu(b.x); v[5] = (short)f2bu(b.y);
  v[6] = (short)f2bu(b.z); v[7] = (short)f2bu(b.w);
  *(short8*)(o + i) = v;
}

// ---------------- gather + convert referenced rows: o[r] = bf16(tab[pairs[2r]])
__global__ void k_cvt_rows(const float* __restrict__ tab, const int* __restrict__ pairs,
                           short* __restrict__ o, int nrows) {
  int t = blockIdx.x * 256 + threadIdx.x;   // one thread = 8 elems
  if (t >= nrows * 32) return;
  int row = t >> 5;
  int c8 = (t & 31) << 3;
  int id = pairs[2 * row];
  const float* s = tab + (size_t)id * 256 + c8;
  float4 a = *(const float4*)(s);
  float4 b = *(const float4*)(s + 4);
  short8 v;
  v[0] = (short)f2bu(a.x); v[1] = (short)f2bu(a.y);
  v[2] = (short)f2bu(a.z); v[3] = (short)f2bu(a.w);
  v[4] = (short)f2bu(b.x); v[5] = (short)f2bu(b.y);
  v[6] = (short)f2bu(b.z); v[7] = (short)f2bu(b.w);
  *(short8*)(o + (size_t)row * 256 + c8) = v;
}

// ---------------- old-layout weight transpose: wt[n*K+k] = w[k*N+n] -------
__global__ void k_wt(const float* __restrict__ w, short* __restrict__ wt, int K, int N) {
  int t = blockIdx.x * 256 + threadIdx.x;
  if (t >= K * N) return;
  int n = t / K;
  int k = t - n * K;
  wt[t] = (short)f2bu(w[(size_t)k * N + n]);
}

// ---------------- swizzled-slab weight layout ---------
// slab ks (32 k's): physical quantum P (16B) holds B[n=P>>2][k=ks*32+kq*8..+7]
// with kq = ((P&3) - (n>>1)) & 3
__global__ void k_wgl(const float* __restrict__ w, short* __restrict__ o, int K, int N) {
  int t = blockIdx.x * 256 + threadIdx.x;
  if (t >= K * N) return;
  int ks = t / (N * 32);
  int rem = t - ks * (N * 32);
  int P = rem >> 3, j = rem & 7;
  int n = P >> 2;
  int kq = ((P & 3) - (n >> 1)) & 3;
  int k = ks * 32 + kq * 8 + j;
  o[t] = (short)f2bu(w[(size_t)k * N + n]);
}

// ---------------- fused g_u(512->256->256) + attu(512->256->16) ----------
// T14 async-STAGE: issue global->reg at iter top, ds_write between two barriers.
// Single-buffered LDS (54.2 KB -> 3 blocks/CU).
template <bool IDENT>
__global__ __launch_bounds__(256, 3) void k_fused(
    const int* __restrict__ idx_pairs,
    const int* __restrict__ qidx_arr,
    const short* __restrict__ tab0,
    const short* __restrict__ tab1,
    const short* __restrict__ itembf,
    const short* __restrict__ zp,
    const short* __restrict__ ws1, const float* __restrict__ b1,
    const short* __restrict__ ws2, const float* __restrict__ b2,
    const short* __restrict__ aw1, const float* __restrict__ ab1,
    const short* __restrict__ aw2t, const float* __restrict__ ab2,
    short* __restrict__ Xout, float* __restrict__ miu_out)
{
  __shared__ __align__(16) short smem[27136];
  short* sA = smem;          // 2048 shorts
  short* sB = smem + 2048;   // 8192 shorts
  short* sH = smem + 10240;  // 16896 = 64 x 264

  const int tid = threadIdx.x;
  const int lane = tid & 63;
  const int wave = tid >> 6;
  const int m0 = (int)blockIdx.x << 6;
  const int l15 = lane & 15;
  const int lq = lane >> 4;
  const int nb = wave << 6;

  const int an = tid >> 2;
  const int kqA = ((tid & 3) - (an >> 1)) & 3;
  const int r = m0 + an;
  const int i0 = idx_pairs[2 * r];
  const int i1 = idx_pairs[2 * r + 1];
  const int qi = qidx_arr[r / 12];
  const short* a0 = (IDENT ? (tab0 + (size_t)r * 256) : (tab0 + (size_t)i0 * 256)) + kqA * 8;
  const short* a1 = tab1 + (size_t)i1 * 256 + kqA * 8;
  const short* aq = ((i0 > 0) ? (itembf + (size_t)qi * 256) : zp) + kqA * 8;

  short* wA = sA + tid * 8;                  // my A quantum (16B)
  short* wB = sB + wave * 2048 + lane * 8;   // my B chunk base
  const short* srcB1 = ws1 + wave * 2048 + lane * 8;
  const short* srcB2 = ws2 + wave * 2048 + lane * 8;
  const short* srcBa = aw1 + wave * 2048 + lane * 8;

  int pA[4], pB[4];
#pragma unroll
  for (int i = 0; i < 4; ++i) {
    int m = i * 16 + l15;
    pA[i] = (m * 4 + ((lq + (m >> 1)) & 3)) * 8;
    int n = nb + i * 16 + l15;
    pB[i] = ((n - nb) * 4 + ((lq + (n >> 1)) & 3)) * 8 + (nb << 5);
  }
  const int hOff = lq * 8;

  const f32x4 fz = {0.f, 0.f, 0.f, 0.f};
  f32x4 acc[4][4];
  short8 rA, rB0, rB1, rB2, rB3;

#pragma unroll
  for (int ni = 0; ni < 4; ++ni)
#pragma unroll
    for (int mi = 0; mi < 4; ++mi) acc[ni][mi] = fz;

  // ================= g_u layer 1 (K=512, 16 ksteps) =================
  rA = *(const short8*)(a0);
  rB0 = *(const short8*)(srcB1);       rB1 = *(const short8*)(srcB1 + 512);
  rB2 = *(const short8*)(srcB1 + 1024); rB3 = *(const short8*)(srcB1 + 1536);
  *(short8*)wA = rA;
  *(short8*)(wB) = rB0; *(short8*)(wB + 512) = rB1;
  *(short8*)(wB + 1024) = rB2; *(short8*)(wB + 1536) = rB3;
  __syncthreads();
  for (int ks = 0; ks < 16; ++ks) {
    if (ks < 15) {
      const int c = ks + 1;
      rA = *(const short8*)((c < 8) ? (a0 + c * 32) : (a1 + (c - 8) * 32));
      const short* s = srcB1 + c * 8192;
      rB0 = *(const short8*)(s);        rB1 = *(const short8*)(s + 512);
      rB2 = *(const short8*)(s + 1024); rB3 = *(const short8*)(s + 1536);
    }
    short8 wf[4], xf[4];
#pragma unroll
    for (int i = 0; i < 4; ++i) {
      wf[i] = *(short8*)(sB + pB[i]);
      xf[i] = *(short8*)(sA + pA[i]);
    }
#pragma unroll
    for (int ni = 0; ni < 4; ++ni)
#pragma unroll
      for (int mi = 0; mi < 4; ++mi)
        acc[ni][mi] = mfma16(wf[ni], xf[mi], acc[ni][mi]);
    __syncthreads();
    if (ks < 15) {
      *(short8*)wA = rA;
      *(short8*)(wB) = rB0; *(short8*)(wB + 512) = rB1;
      *(short8*)(wB + 1024) = rB2; *(short8*)(wB + 1536) = rB3;
    }
    __syncthreads();
  }
  // hidden = relu(+b1) -> sH
#pragma unroll
  for (int ni = 0; ni < 4; ++ni) {
    const int nbase = nb + ni * 16 + lq * 4;
    float4 bb = *(const float4*)(b1 + nbase);
#pragma unroll
    for (int mi = 0; mi < 4; ++mi) {
      const int m = mi * 16 + l15;
      short4v hv;
      hv[0] = (short)f2bu(fmaxf(acc[ni][mi][0] + bb.x, 0.f));
      hv[1] = (short)f2bu(fmaxf(acc[ni][mi][1] + bb.y, 0.f));
      hv[2] = (short)f2bu(fmaxf(acc[ni][mi][2] + bb.z, 0.f));
      hv[3] = (short)f2bu(fmaxf(acc[ni][mi][3] + bb.w, 0.f));
      *(short4v*)(sH + m * 264 + nbase) = hv;
    }
  }

  // ================= g_u layer 2 (K=256, A from sH) =================
#pragma unroll
  for (int ni = 0; ni < 4; ++ni)
#pragma unroll
    for (int mi = 0; mi < 4; ++mi) acc[ni][mi] = fz;
  rB0 = *(const short8*)(srcB2);        rB1 = *(const short8*)(srcB2 + 512);
  rB2 = *(const short8*)(srcB2 + 1024); rB3 = *(const short8*)(srcB2 + 1536);
  *(short8*)(wB) = rB0; *(short8*)(wB + 512) = rB1;
  *(short8*)(wB + 1024) = rB2; *(short8*)(wB + 1536) = rB3;
  __syncthreads();   // also publishes sH
  for (int ks = 0; ks < 8; ++ks) {
    if (ks < 7) {
      const short* s = srcB2 + (ks + 1) * 8192;
      rB0 = *(const short8*)(s);        rB1 = *(const short8*)(s + 512);
      rB2 = *(const short8*)(s + 1024); rB3 = *(const short8*)(s + 1536);
    }
    short8 wf[4], hf[4];
#pragma unroll
    for (int i = 0; i < 4; ++i) {
      wf[i] = *(short8*)(sB + pB[i]);
      hf[i] = *(short8*)(sH + (i * 16 + l15) * 264 + ks * 32 + hOff);
    }
#pragma unroll
    for (int ni = 0; ni < 4; ++ni)
#pragma unroll
      for (int mi = 0; mi < 4; ++mi)
        acc[ni][mi] = mfma16(wf[ni], hf[mi], acc[ni][mi]);
    __syncthreads();
    if (ks < 7) {
      *(short8*)(wB) = rB0; *(short8*)(wB + 512) = rB1;
      *(short8*)(wB + 1024) = rB2; *(short8*)(wB + 1536) = rB3;
    }
    __syncthreads();
  }
  // f_jt = acc + b2 -> X global + sH
#pragma unroll
  for (int ni = 0; ni < 4; ++ni) {
    const int nbase = nb + ni * 16 + lq * 4;
    float4 bb = *(const float4*)(b2 + nbase);
#pragma unroll
    for (int mi = 0; mi < 4; ++mi) {
      const int m = mi * 16 + l15;
      short4v hv;
      hv[0] = (short)f2bu(acc[ni][mi][0] + bb.x);
      hv[1] = (short)f2bu(acc[ni][mi][1] + bb.y);
      hv[2] = (short)f2bu(acc[ni][mi][2] + bb.z);
      hv[3] = (short)f2bu(acc[ni][mi][3] + bb.w);
      *(short4v*)(sH + m * 264 + nbase) = hv;
      *(short4v*)(Xout + (size_t)(m0 + m) * 256 + nbase) = hv;
    }
  }

  // ================= attn layer 1 (K=512: sH | staged Q) =================
#pragma unroll
  for (int ni = 0; ni < 4; ++ni)
#pragma unroll
    for (int mi = 0; mi < 4; ++mi) acc[ni][mi] = fz;
  rB0 = *(const short8*)(srcBa);        rB1 = *(const short8*)(srcBa + 512);
  rB2 = *(const short8*)(srcBa + 1024); rB3 = *(const short8*)(srcBa + 1536);
  *(short8*)(wB) = rB0; *(short8*)(wB + 512) = rB1;
  *(short8*)(wB + 1024) = rB2; *(short8*)(wB + 1536) = rB3;
  __syncthreads();
  for (int ks = 0; ks < 16; ++ks) {
    const bool pf = (ks < 15);
    const bool pfA = pf && (ks + 1 >= 8);
    if (pf) {
      const short* s = srcBa + (ks + 1) * 8192;
      rB0 = *(const short8*)(s);        rB1 = *(const short8*)(s + 512);
      rB2 = *(const short8*)(s + 1024); rB3 = *(const short8*)(s + 1536);
      if (pfA) rA = *(const short8*)(aq + (ks + 1 - 8) * 32);
    }
    short8 wf[4], xf[4];
#pragma unroll
    for (int i = 0; i < 4; ++i) wf[i] = *(short8*)(sB + pB[i]);
    if (ks < 8) {
#pragma unroll
      for (int i = 0; i < 4; ++i)
        xf[i] = *(short8*)(sH + (i * 16 + l15) * 264 + ks * 32 + hOff);
    } else {
#pragma unroll
      for (int i = 0; i < 4; ++i) xf[i] = *(short8*)(sA + pA[i]);
    }
#pragma unroll
    for (int ni = 0; ni < 4; ++ni)
#pragma unroll
      for (int mi = 0; mi < 4; ++mi)
        acc[ni][mi] = mfma16(wf[ni], xf[mi], acc[ni][mi]);
    __syncthreads();
    if (pf) {
      *(short8*)(wB) = rB0; *(short8*)(wB + 512) = rB1;
      *(short8*)(wB + 1024) = rB2; *(short8*)(wB + 1536) = rB3;
      if (pfA) *(short8*)wA = rA;
    }
    __syncthreads();
  }
  // attn hidden = relu(+ab1) -> sH (overwrite)
#pragma unroll
  for (int ni = 0; ni < 4; ++ni) {
    const int nbase = nb + ni * 16 + lq * 4;
    float4 bb = *(const float4*)(ab1 + nbase);
#pragma unroll
    for (int mi = 0; mi < 4; ++mi) {
      const int m = mi * 16 + l15;
      short4v hv;
      hv[0] = (short)f2bu(fmaxf(acc[ni][mi][0] + bb.x, 0.f));
      hv[1] = (short)f2bu(fmaxf(acc[ni][mi][1] + bb.y, 0.f));
      hv[2] = (short)f2bu(fmaxf(acc[ni][mi][2] + bb.z, 0.f));
      hv[3] = (short)f2bu(fmaxf(acc[ni][mi][3] + bb.w, 0.f));
      *(short4v*)(sH + m * 264 + nbase) = hv;
    }
  }
  // stage W2 (16 x 256) into region aliasing sA/sB
  {
    short* W2s = smem;
    const int rw = tid & 15, seg = (tid >> 4) << 4;
    *(short8*)(W2s + rw * 264 + seg)     = *(const short8*)(aw2t + rw * 256 + seg);
    *(short8*)(W2s + rw * 264 + seg + 8) = *(const short8*)(aw2t + rw * 256 + seg + 8);
  }
  __syncthreads();

  // ================= attn layer 2 (256 -> 16) ==========
  f32x4 a2 = fz;
#pragma unroll
  for (int ks = 0; ks < 8; ++ks) {
    short8 af = *(short8*)(sH + (wave * 16 + l15) * 264 + ks * 32 + hOff);
    short8 bv = *(short8*)(smem + l15 * 264 + ks * 32 + hOff);
    a2 = mfma16(af, bv, a2);
  }
  const float bias = ab2[l15];
#pragma unroll
  for (int j = 0; j < 4; ++j)
    miu_out[(size_t)(m0 + wave * 16 + lq * 4 + j) * 16 + l15] = a2[j] + bias;
}

// ---------------- kappa scores: concat(first[r], itembf[iidx[r]]) -> 16 ---
__global__ __launch_bounds__(256, 3) void k_attonly(
    const short* __restrict__ first,
    const short* __restrict__ itembf,
    const int* __restrict__ iidx,
    const short* __restrict__ aw1, const float* __restrict__ ab1,
    const short* __restrict__ aw2t, const float* __restrict__ ab2,
    float* __restrict__ out)
{
  __shared__ __align__(16) short smem[27136];
  short* sA = smem;
  short* sB = smem + 2048;
  short* sH = smem + 10240;

  const int tid = threadIdx.x;
  const int lane = tid & 63;
  const int wave = tid >> 6;
  const int m0 = (int)blockIdx.x << 6;
  const int l15 = lane & 15;
  const int lq = lane >> 4;
  const int nb = wave << 6;

  const int an = tid >> 2;
  const int kqA = ((tid & 3) - (an >> 1)) & 3;
  const int r = m0 + an;
  const short* aF = first + (size_t)r * 256 + kqA * 8;
  const short* aq = itembf + (size_t)iidx[r] * 256 + kqA * 8;

  short* wA = sA + tid * 8;
  short* wB = sB + wave * 2048 + lane * 8;
  const short* srcB = aw1 + wave * 2048 + lane * 8;

  int pA[4], pB[4];
#pragma unroll
  for (int i = 0; i < 4; ++i) {
    int m = i * 16 + l15;
    pA[i] = (m * 4 + ((lq + (m >> 1)) & 3)) * 8;
    int n = nb + i * 16 + l15;
    pB[i] = ((n - nb) * 4 + ((lq + (n >> 1)) & 3)) * 8 + (nb << 5);
  }
  const int hOff = lq * 8;

  const f32x4 fz = {0.f, 0.f, 0.f, 0.f};
  f32x4 acc[4][4];
  short8 rA, rB0, rB1, rB2, rB3;
#pragma unroll
  for (int ni = 0; ni < 4; ++ni)
#pragma unroll
    for (int mi = 0; mi < 4; ++mi) acc[ni][mi] = fz;

  rA = *(const short8*)(aF);
  rB0 = *(const short8*)(srcB);        rB1 = *(const short8*)(srcB + 512);
  rB2 = *(const short8*)(srcB + 1024); rB3 = *(const short8*)(srcB + 1536);
  *(short8*)wA = rA;
  *(short8*)(wB) = rB0; *(short8*)(wB + 512) = rB1;
  *(short8*)(wB + 1024) = rB2; *(short8*)(wB + 1536) = rB3;
  __syncthreads();
  for (int ks = 0; ks < 16; ++ks) {
    if (ks < 15) {
      const int c = ks + 1;
      rA = *(const short8*)((c < 8) ? (aF + c * 32) : (aq + (c - 8) * 32));
      const short* s = srcB + c * 8192;
      rB0 = *(const short8*)(s);        rB1 = *(const short8*)(s + 512);
      rB2 = *(const short8*)(s + 1024); rB3 = *(const short8*)(s + 1536);
    }
    short8 wf[4], xf[4];
#pragma unroll
    for (int i = 0; i < 4; ++i) {
      wf[i] = *(short8*)(sB + pB[i]);
      xf[i] = *(short8*)(sA + pA[i]);
    }
#pragma unroll
    for (int ni = 0; ni < 4; ++ni)
#pragma unroll
      for (int mi = 0; mi < 4; ++mi)
        acc[ni][mi] = mfma16(wf[ni], xf[mi], acc[ni][mi]);
    __syncthreads();
    if (ks < 15) {
      *(short8*)wA = rA;
      *(short8*)(wB) = rB0; *(short8*)(wB + 512) = rB1;
      *(short8*)(wB + 1024) = rB2; *(short8*)(wB + 1536) = rB3;
    }
    __syncthreads();
  }
#pragma unroll
  for (int ni = 0; ni < 4; ++ni) {
    const int nbase = nb + ni * 16 + lq * 4;
    float4 bb = *(const float4*)(ab1 + nbase);
#pragma unroll
    for (int mi = 0; mi < 4; ++mi) {
      const int m = mi * 16 + l15;
      short4v hv;
      hv[0] = (short)f2bu(fmaxf(acc[ni][mi][0] + bb.x, 0.f));
      hv[1] = (short)f2bu(fmaxf(acc[ni][mi][1] + bb.y, 0.f));
      hv[2] = (short)f2bu(fmaxf(acc[ni][mi][2] + bb.z, 0.f));
      hv[3] = (short)f2bu(fmaxf(acc[ni][mi][3] + bb.w, 0.f));
      *(short4v*)(sH + m * 264 + nbase) = hv;
    }
  }
  {
    short* W2s = smem;
    const int rw = tid & 15, seg = (tid >> 4) << 4;
    *(short8*)(W2s + rw * 264 + seg)     = *(const short8*)(aw2t + rw * 256 + seg);
    *(short8*)(W2s + rw * 264 + seg + 8) = *(const short8*)(aw2t + rw * 256 + seg + 8);
  }
  __syncthreads();
  f32x4 a2 = fz;
#pragma unroll
  for (int ks = 0; ks < 8; ++ks) {
    short8 af = *(short8*)(sH + (wave * 16 + l15) * 264 + ks * 32 + hOff);
    short8 bv = *(short8*)(smem + l15 * 264 + ks * 32 + hOff);
    a2 = mfma16(af, bv, a2);
  }
  const float bias = ab2[l15];
#pragma unroll
  for (int j = 0; j < 4; ++j)
    out[(size_t)(m0 + wave * 16 + lq * 4 + j) * 16 + l15] = a2[j] + bias;
}

// ---------------- single-layer GEMM 256->256 + bias + relu ----------------
__global__ __launch_bounds__(256, 2) void k_gemm1(
    const short* __restrict__ Abf, const short* __restrict__ wt,
    const float* __restrict__ bias, short* __restrict__ out)
{
  __shared__ __align__(16) short smem[12800];
  short (*A)[40]  = (short(*)[40])smem;
  short (*Bt)[40] = (short(*)[40])(smem + 2560);

  const int tid  = threadIdx.x;
  const int lane = tid & 63;
  const int wave = tid >> 6;
  const int m0   = blockIdx.x << 6;
  const int arow = tid >> 2;
  const int acol8 = (tid & 3) << 3;
  const int lrow = lane & 15;
  const int lk8  = (lane >> 4) << 3;
  const int rq   = (lane >> 4) << 2;
  const int nb   = wave << 6;
  const int r = m0 + arow;

  const f32x4 fz = {0.f, 0.f, 0.f, 0.f};
  f32x4 acc[4][4];
#pragma unroll
  for (int mi = 0; mi < 4; ++mi)
#pragma unroll
    for (int ni = 0; ni < 4; ++ni) acc[mi][ni] = fz;

  for (int ks = 0; ks < 8; ++ks) {
    *(short8*)&A[arow][acol8] = *(const short8*)(Abf + (size_t)r * 256 + (ks << 5) + acol8);
    const short* wsrc = wt + tid * 256 + (ks << 5);
    *(short8*)&Bt[tid][0]  = *(const short8*)(wsrc);
    *(short8*)&Bt[tid][8]  = *(const short8*)(wsrc + 8);
    *(short8*)&Bt[tid][16] = *(const short8*)(wsrc + 16);
    *(short8*)&Bt[tid][24] = *(const short8*)(wsrc + 24);
    __syncthreads();
    short8 af[4], bv[4];
#pragma unroll
    for (int mi = 0; mi < 4; ++mi) af[mi] = *(short8*)&A[mi * 16 + lrow][lk8];
#pragma unroll
    for (int ni = 0; ni < 4; ++ni) bv[ni] = *(short8*)&Bt[nb + ni * 16 + lrow][lk8];
#pragma unroll
    for (int mi = 0; mi < 4; ++mi)
#pragma unroll
      for (int ni = 0; ni < 4; ++ni)
        acc[mi][ni] = mfma16(af[mi], bv[ni], acc[mi][ni]);
    __syncthreads();
  }

#pragma unroll
  for (int ni = 0; ni < 4; ++ni) {
    const int col = nb + ni * 16 + lrow;
    const float b = bias[col];
#pragma unroll
    for (int mi = 0; mi < 4; ++mi)
#pragma unroll
      for (int j = 0; j < 4; ++j) {
        const int row = mi * 16 + rq + j;
        out[(size_t)(m0 + row) * 256 + col] = (short)f2bu(fmaxf(acc[mi][ni][j] + b, 0.f));
      }
  }
}

// ---------------- fused 3-layer comb MLP --------------------------------
__global__ __launch_bounds__(256, 2) void k_comb(
    const short* __restrict__ hju, const short* __restrict__ hjv,
    const short* __restrict__ w1t, const float* __restrict__ b1,
    const short* __restrict__ w2t, const float* __restrict__ b2,
    const short* __restrict__ w3t, const float* __restrict__ b3,
    float* __restrict__ out)
{
  __shared__ __align__(16) short smem[29696];
  short (*A)[40]   = (short(*)[40])smem;
  short (*Bt)[40]  = (short(*)[40])(smem + 2560);
  short (*Hh)[264] = (short(*)[264])(smem + 12800);

  const int tid  = threadIdx.x;
  const int lane = tid & 63;
  const int wave = tid >> 6;
  const int m0   = blockIdx.x << 6;
  const int arow = tid >> 2;
  const int acol8 = (tid & 3) << 3;
  const int lrow = lane & 15;
  const int lk8  = (lane >> 4) << 3;
  const int rq   = (lane >> 4) << 2;
  const int nb   = wave << 6;
  const int r = m0 + arow;

  const f32x4 fz = {0.f, 0.f, 0.f, 0.f};
  f32x4 acc[4][4];
#pragma unroll
  for (int mi = 0; mi < 4; ++mi)
#pragma unroll
    for (int ni = 0; ni < 4; ++ni) acc[mi][ni] = fz;

  for (int ks = 0; ks < 16; ++ks) {
    const int kg = (ks << 5) + acol8;
    short8 av = (kg < 256) ? *(const short8*)(hju + (size_t)r * 256 + kg)
                           : *(const short8*)(hjv + (size_t)r * 256 + (kg - 256));
    *(short8*)&A[arow][acol8] = av;
    const short* wsrc = w1t + tid * 512 + (ks << 5);
    *(short8*)&Bt[tid][0]  = *(const short8*)(wsrc);
    *(short8*)&Bt[tid][8]  = *(const short8*)(wsrc + 8);
    *(short8*)&Bt[tid][16] = *(const short8*)(wsrc + 16);
    *(short8*)&Bt[tid][24] = *(const short8*)(wsrc + 24);
    __syncthreads();
    short8 af[4], bv[4];
#pragma unroll
    for (int mi = 0; mi < 4; ++mi) af[mi] = *(short8*)&A[mi * 16 + lrow][lk8];
#pragma unroll
    for (int ni = 0; ni < 4; ++ni) bv[ni] = *(short8*)&Bt[nb + ni * 16 + lrow][lk8];
#pragma unroll
    for (int mi = 0; mi < 4; ++mi)
#pragma unroll
      for (int ni = 0; ni < 4; ++ni)
        acc[mi][ni] = mfma16(af[mi], bv[ni], acc[mi][ni]);
    __syncthreads();
  }
#pragma unroll
  for (int ni = 0; ni < 4; ++ni) {
    const int col = nb + ni * 16 + lrow;
    const float bias = b1[col];
#pragma unroll
    for (int mi = 0; mi < 4; ++mi)
#pragma unroll
      for (int j = 0; j < 4; ++j)
        Hh[mi * 16 + rq + j][col] = (short)f2bu(fmaxf(acc[mi][ni][j] + bias, 0.f));
  }

#pragma unroll
  for (int mi = 0; mi < 4; ++mi)
#pragma unroll
    for (int ni = 0; ni < 4; ++ni) acc[mi][ni] = fz;
  for (int ks = 0; ks < 8; ++ks) {
    const short* wsrc = w2t + tid * 256 + (ks << 5);
    *(short8*)&Bt[tid][0]  = *(const short8*)(wsrc);
    *(short8*)&Bt[tid][8]  = *(const short8*)(wsrc + 8);
    *(short8*)&Bt[tid][16] = *(const short8*)(wsrc + 16);
    *(short8*)&Bt[tid][24] = *(const short8*)(wsrc + 24);
    __syncthreads();
    short8 af[4], bv[4];
#pragma unroll
    for (int mi = 0; mi < 4; ++mi) af[mi] = *(short8*)&Hh[mi * 16 + lrow][(ks << 5) + lk8];
#pragma unroll
    for (int ni = 0; ni < 4; ++ni) bv[ni] = *(short8*)&Bt[nb + ni * 16 + lrow][lk8];
#pragma unroll
    for (int mi = 0; mi < 4; ++mi)
#pragma unroll
      for (int ni = 0; ni < 4; ++ni)
        acc[mi][ni] = mfma16(af[mi], bv[ni], acc[mi][ni]);
    __syncthreads();
  }
#pragma unroll
  for (int ni = 0; ni < 4; ++ni) {
    const int col = nb + ni * 16 + lrow;
    const float bias = b2[col];
#pragma unroll
    for (int mi = 0; mi < 4; ++mi)
#pragma unroll
      for (int j = 0; j < 4; ++j)
        Hh[mi * 16 + rq + j][col] = (short)f2bu(fmaxf(acc[mi][ni][j] + bias, 0.f));
  }
  __syncthreads();

#pragma unroll
  for (int mi = 0; mi < 4; ++mi)
#pragma unroll
    for (int ni = 0; ni < 4; ++ni) acc[mi][ni] = fz;
  for (int ks = 0; ks < 8; ++ks) {
    const short* wsrc = w3t + tid * 256 + (ks << 5);
    *(short8*)&Bt[tid][0]  = *(const short8*)(wsrc);
    *(short8*)&Bt[tid][8]  = *(const short8*)(wsrc + 8);
    *(short8*)&Bt[tid][16] = *(const short8*)(wsrc + 16);
    *(short8*)&Bt[tid][24] = *(const short8*)(wsrc + 24);
    __syncthreads();
    short8 af[4], bv[4];
#pragma unroll
    for (int mi = 0; mi < 4; ++mi) af[mi] = *(short8*)&Hh[mi * 16 + lrow][(ks << 5) + lk8];
#pragma unroll
    for (int ni = 0; ni < 4; ++ni) bv[ni] = *(short8*)&Bt[nb + ni * 16 + lrow][lk8];
#pragma unroll
    for (int mi = 0; mi < 4; ++mi)
#pragma unroll
      for (int ni = 0; ni < 4; ++ni)
        acc[mi][ni] = mfma16(af[mi], bv[ni], acc[mi][ni]);
    __syncthreads();
  }
#pragma unroll
  for (int ni = 0; ni < 4; ++ni) {
    const int col = nb + ni * 16 + lrow;
    const float bias = b3[col];
#pragma unroll
    for (int mi = 0; mi < 4; ++mi)
#pragma unroll
      for (int j = 0; j < 4; ++j) {
        const int row = mi * 16 + rq + j;
        out[(size_t)(m0 + row) * 256 + col] = fmaxf(acc[mi][ni][j] + bias, 0.f);
      }
  }
}

// ---------------- head MLP + softmax + weighted sum, 16 groups/block ------
__global__ __launch_bounds__(256) void k_headg(
    const float* __restrict__ miu_in,   // [G][192]
    const int* __restrict__ mask_src, const int mstride,
    const short* __restrict__ src,      // [G*12][256] bf16
    const float* __restrict__ w1, const float* __restrict__ b1,
    const float* __restrict__ w2, const float* __restrict__ b2,
    short* __restrict__ outp)           // [G][256] bf16
{
  __shared__ float in_s[16][192];
  __shared__ float h1[16][96];
  __shared__ float wgt[16][12];

  const int tid = threadIdx.x;
  const int g0 = blockIdx.x * 16;
  // stage miu (16*192 = 3072 f32)
#pragma unroll
  for (int it = 0; it < 12; ++it) {
    int i = it * 256 + tid;
    ((float*)in_s)[i] = miu_in[(size_t)g0 * 192 + i];
  }
  __syncthreads();
  const int g = tid >> 4, sl = tid & 15;
  // layer 1: 192 -> 96, j = sl + 16*jj
#pragma unroll
  for (int jj = 0; jj < 6; ++jj) {
    const int j = sl + 16 * jj;
    float s = b1[j];
    for (int k = 0; k < 192; k += 4) {
      s += in_s[g][k]     * w1[k * 96 + j];
      s += in_s[g][k + 1] * w1[(k + 1) * 96 + j];
      s += in_s[g][k + 2] * w1[(k + 2) * 96 + j];
      s += in_s[g][k + 3] * w1[(k + 3) * 96 + j];
    }
    h1[g][j] = fmaxf(s, 0.f);
  }
  __syncthreads();
  // layer 2: 96 -> 12, + mask + exp
  if (sl < 12) {
    float s = b2[sl];
#pragma unroll 4
    for (int k = 0; k < 96; ++k) s += h1[g][k] * w2[k * 12 + sl];
    const int gid = g0 + g;
    const int mi = mask_src[(gid * 12 + sl) * mstride];
    wgt[g][sl] = (mi > 0) ? expf(s) : 0.f;
  }
  __syncthreads();
  float tot = 1e-10f;
#pragma unroll
  for (int m = 0; m < 12; ++m) tot += wgt[g][m];
  const float inv = 1.f / tot;

  // weighted sum: thread = (g, 16 cols at sl*16)
  float o[16];
#pragma unroll
  for (int j = 0; j < 16; ++j) o[j] = 0.f;
  const short* sp = src + ((size_t)(g0 + g) * 12) * 256 + sl * 16;
#pragma unroll
  for (int m = 0; m < 12; ++m) {
    const float wm = wgt[g][m] * inv;
    short8 x0 = *(const short8*)(sp + m * 256);
    short8 x1 = *(const short8*)(sp + m * 256 + 8);
#pragma unroll
    for (int j = 0; j < 8; ++j) {
      o[j]     += wm * b2f((unsigned short)x0[j]);
      o[8 + j] += wm * b2f((unsigned short)x1[j]);
    }
  }
  short8 v0, v1;
#pragma unroll
  for (int j = 0; j < 8; ++j) {
    v0[j] = (short)f2bu(o[j]);
    v1[j] = (short)f2bu(o[8 + j]);
  }
  short* op = outp + (size_t)(g0 + g) * 256 + sl * 16;
  *(short8*)(op) = v0;
  *(short8*)(op + 8) = v1;
}

// =====================================================================
extern "C" void kernel_launch(void* const* d_in, const int* in_sizes, int n_in,
                              void* d_out, int out_size, void* d_ws, size_t ws_size,
                              hipStream_t stream)
{
  (void)in_sizes; (void)n_in; (void)out_size; (void)ws_size;

  const int*   iids = (const int*)d_in[0];
  const int*   iup  = (const int*)d_in[1];
  const int*   iip  = (const int*)d_in[2];
  const int*   iiup = (const int*)d_in[3];
  const float* user_table = (const float*)d_in[4];
  const float* item_table = (const float*)d_in[5];
  const float* rate_table = (const float*)d_in[6];
  const float* g_u_w1 = (const float*)d_in[7];   const float* g_u_b1 = (const float*)d_in[8];
  const float* g_u_w2 = (const float*)d_in[9];   const float* g_u_b2 = (const float*)d_in[10];
  const float* attu_w1 = (const float*)d_in[11]; const float* attu_b1 = (const float*)d_in[12];
  const float* attu_w2 = (const float*)d_in[13]; const float* attu_b2 = (const float*)d_in[14];
  const float* headu_w1 = (const float*)d_in[15]; const float* headu_b1 = (const float*)d_in[16];
  const float* headu_w2 = (const float*)d_in[17]; const float* headu_b2 = (const float*)d_in[18];
  const float* aggi_w = (const float*)d_in[19];  const float* aggi_b = (const float*)d_in[20];
  const float* attii_w1 = (const float*)d_in[21]; const float* attii_b1 = (const float*)d_in[22];
  const float* attii_w2 = (const float*)d_in[23]; const float* attii_b2 = (const float*)d_in[24];
  const float* headii_w1 = (const float*)d_in[25]; const float* headii_b1 = (const float*)d_in[26];
  const float* headii_w2 = (const float*)d_in[27]; const float* headii_b2 = (const float*)d_in[28];
  const float* aggii_w = (const float*)d_in[29]; const float* aggii_b = (const float*)d_in[30];
  const float* comb_w1 = (const float*)d_in[31]; const float* comb_b1 = (const float*)d_in[32];
  const float* comb_w2 = (const float*)d_in[33]; const float* comb_b2 = (const float*)d_in[34];
  const float* comb_w3 = (const float*)d_in[35]; const float* comb_b3 = (const float*)d_in[36];

  const int NIe = 100000 * 256, NRe = 6 * 256;
  const int M2 = 2048 * 12 * 12;
  const int M1 = 2048 * 12;

  char* wsp = (char*)d_ws;
  size_t off = 0;
  auto alloc = [&](size_t bytes) -> void* {
    void* p = wsp + off;
    off += (bytes + 255) & ~(size_t)255;
    return p;
  };
  short* item_bf = (short*)alloc((size_t)NIe * 2);
  short* rate_bf = (short*)alloc((size_t)NRe * 2);
  short* urows   = (short*)alloc((size_t)M1 * 256 * 2);
  short* zp      = (short*)alloc(512);
  short* sl_gu1   = (short*)alloc((size_t)512 * 256 * 2);
  short* sl_gu2   = (short*)alloc((size_t)256 * 256 * 2);
  short* sl_attu1 = (short*)alloc((size_t)512 * 256 * 2);
  short* sl_attii1= (short*)alloc((size_t)512 * 256 * 2);
  short* wt_attu2 = (short*)alloc((size_t)256 * 16 * 2);
  short* wt_attii2= (short*)alloc((size_t)256 * 16 * 2);
  short* wt_aggi   = (short*)alloc((size_t)256 * 256 * 2);
  short* wt_aggii  = (short*)alloc((size_t)256 * 256 * 2);
  short* wt_comb1  = (short*)alloc((size_t)512 * 256 * 2);
  short* wt_comb2  = (short*)alloc((size_t)256 * 256 * 2);
  short* wt_comb3  = (short*)alloc((size_t)256 * 256 * 2);

  short* X      = (short*)alloc((size_t)M2 * 256 * 2);
  short* FJT    = (short*)alloc((size_t)M1 * 256 * 2);
  float* MIU2   = (float*)alloc((size_t)M2 * 16 * 4);
  float* MIU1   = (float*)alloc((size_t)M1 * 16 * 4);
  float* KAP    = (float*)alloc((size_t)M1 * 16 * 4);
  short* HPRE2  = (short*)alloc((size_t)M1 * 256 * 2);
  short* HOU    = (short*)alloc((size_t)M1 * 256 * 2);
  short* HPREJV = (short*)alloc((size_t)2048 * 256 * 2);
  short* HPRE1  = (short*)alloc((size_t)2048 * 256 * 2);
  short* HJU    = (short*)alloc((size_t)2048 * 256 * 2);
  short* HJV    = (short*)alloc((size_t)2048 * 256 * 2);

  hipMemsetAsync(zp, 0, 512, stream);
  k_cvt<<<NIe / 8 / 256, 256, 0, stream>>>(item_table, item_bf, NIe);
  k_cvt<<<1, 256, 0, stream>>>(rate_table, rate_bf, NRe);
  k_cvt_rows<<<(M1 * 32) / 256, 256, 0, stream>>>(user_table, iup, urows, M1);

  auto wgl = [&](const float* w, short* dst, int K, int N) {
    k_wgl<<<(K * N + 255) / 256, 256, 0, stream>>>(w, dst, K, N);
  };
  auto wtl = [&](const float* w, short* dst, int K, int N) {
    k_wt<<<(K * N + 255) / 256, 256, 0, stream>>>(w, dst, K, N);
  };
  wgl(g_u_w1, sl_gu1, 512, 256);
  wgl(g_u_w2, sl_gu2, 256, 256);
  wgl(attu_w1, sl_attu1, 512, 256);
  wgl(attii_w1, sl_attii1, 512, 256);
  wtl(attu_w2, wt_attu2, 256, 16);
  wtl(attii_w2, wt_attii2, 256, 16);
  wtl(aggi_w, wt_aggi, 256, 256);
  wtl(aggii_w, wt_aggii, 256, 256);
  wtl(comb_w1, wt_comb1, 512, 256);
  wtl(comb_w2, wt_comb2, 256, 256);
  wtl(comb_w3, wt_comb3, 256, 256);

  // fused g_u + attu : part-2 inner (dominant), then part-1
  k_fused<false><<<M2 / 64, 256, 0, stream>>>(iiup, iip, item_bf, rate_bf, item_bf, zp,
                                              sl_gu1, g_u_b1, sl_gu2, g_u_b2,
                                              sl_attu1, attu_b1, wt_attu2, attu_b2,
                                              X, MIU2);
  k_fused<true><<<M1 / 64, 256, 0, stream>>>(iup, iids, urows, rate_bf, item_bf, zp,
                                             sl_gu1, g_u_b1, sl_gu2, g_u_b2,
                                             sl_attu1, attu_b1, wt_attu2, attu_b2,
                                             FJT, MIU1);

  k_headg<<<M1 / 16, 256, 0, stream>>>(MIU2, iiup, 2, X,
                                       headu_w1, headu_b1, headu_w2, headu_b2, HPRE2);
  k_gemm1<<<M1 / 64, 256, 0, stream>>>(HPRE2, wt_aggi, aggi_b, HOU);
  k_attonly<<<M1 / 64, 256, 0, stream>>>(HOU, item_bf, iip,
                                         sl_attii1, attii_b1, wt_attii2, attii_b2, KAP);
  k_headg<<<2048 / 16, 256, 0, stream>>>(KAP, iip, 1, HOU,
                                         headii_w1, headii_b1, headii_w2, headii_b2, HPREJV);
  k_headg<<<2048 / 16, 256, 0, stream>>>(MIU1, iup, 2, FJT,
                                         headu_w1, headu_b1, headu_w2, headu_b2, HPRE1);
  k_gemm1<<<2048 / 64, 256, 0, stream>>>(HPRE1, wt_aggi, aggi_b, HJU);
  k_gemm1<<<2048 / 64, 256, 0, stream>>>(HPREJV, wt_aggii, aggii_b, HJV);
  k_comb<<<2048 / 64, 256, 0, stream>>>(HJU, HJV, wt_comb1, comb_b1,
                                        wt_comb2, comb_b2, wt_comb3, comb_b3,
                                        (float*)d_out);
}

// Round 4
// 573.693 us; speedup vs baseline: 1.4537x; 1.1159x over previous
//
#include <hip/hip_runtime.h>
#include <cstdint>
#include <cstddef>

typedef short short8 __attribute__((ext_vector_type(8)));
typedef short short4v __attribute__((ext_vector_type(4)));
typedef float f32x4 __attribute__((ext_vector_type(4)));
typedef __bf16 bf16x8 __attribute__((ext_vector_type(8)));

__device__ __forceinline__ unsigned short f2bu(float f) {
  union { float f; unsigned u; } v; v.f = f;
  unsigned r = v.u + 0x7FFFu + ((v.u >> 16) & 1u);
  return (unsigned short)(r >> 16);
}
__device__ __forceinline__ float b2f(unsigned short h) {
  union { unsigned u; float f; } v; v.u = ((unsigned)h) << 16;
  return v.f;
}

__device__ __forceinline__ f32x4 mfma16(short8 a, short8 b, f32x4 c) {
  return __builtin_amdgcn_mfma_f32_16x16x32_bf16(
      __builtin_bit_cast(bf16x8, a), __builtin_bit_cast(bf16x8, b), c, 0, 0, 0);
}

// ---------------- f32 -> bf16 table convert (8/thread) ----------------
__global__ void k_cvt(const float* __restrict__ in, short* __restrict__ o, int ntot) {
  int i = (blockIdx.x * 256 + threadIdx.x) * 8;
  if (i >= ntot) return;
  float4 a = *(const float4*)(in + i);
  float4 b = *(const float4*)(in + i + 4);
  short8 v;
  v[0] = (short)f2bu(a.x); v[1] = (short)f2bu(a.y);
  v[2] = (short)f2bu(a.z); v[3] = (short)f2bu(a.w);
  v[4] = (short)f2bu(b.x); v[5] = (short)f2bu(b.y);
  v[6] = (short)f2bu(b.z); v[7] = (short)f2bu(b.w);
  *(short8*)(o + i) = v;
}

// ---------------- gather + convert referenced rows ------------------------
__global__ void k_cvt_rows(const float* __restrict__ tab, const int* __restrict__ pairs,
                           short* __restrict__ o, int nrows) {
  int t = blockIdx.x * 256 + threadIdx.x;
  if (t >= nrows * 32) return;
  int row = t >> 5;
  int c8 = (t & 31) << 3;
  int id = pairs[2 * row];
  const float* s = tab + (size_t)id * 256 + c8;
  float4 a = *(const float4*)(s);
  float4 b = *(const float4*)(s + 4);
  short8 v;
  v[0] = (short)f2bu(a.x); v[1] = (short)f2bu(a.y);
  v[2] = (short)f2bu(a.z); v[3] = (short)f2bu(a.w);
  v[4] = (short)f2bu(b.x); v[5] = (short)f2bu(b.y);
  v[6] = (short)f2bu(b.z); v[7] = (short)f2bu(b.w);
  *(short8*)(o + (size_t)row * 256 + c8) = v;
}

// ---------------- merged weight prep (slab-swizzle / transpose / cvt) -----
struct Prep {
  const float* src[12];
  short* dst[12];
  int K[12], N[12], mode[12];   // mode 0 = slab(N=256), 1 = transpose, 2 = cvt
  int boff[13];
};
__global__ void k_prep(Prep p) {
  int b = blockIdx.x, e = 0;
#pragma unroll
  for (int i = 1; i < 12; ++i) if (b >= p.boff[i]) e = i;
  int t = (b - p.boff[e]) * 256 + threadIdx.x;
  const float* w = p.src[e];
  short* o = p.dst[e];
  const int m = p.mode[e];
  if (m == 2) { o[t] = (short)f2bu(w[t]); return; }
  if (m == 0) {
    int ks = t >> 13, rem = t & 8191;
    int P = rem >> 3, j = rem & 7;
    int n = P >> 2;
    int kq = ((P & 3) - (n >> 1)) & 3;
    int k = (ks << 5) + (kq << 3) + j;
    o[t] = (short)f2bu(w[(size_t)k * 256 + n]);
  } else {
    int K = p.K[e], N = p.N[e];
    int n = t / K, k = t - n * K;
    o[t] = (short)f2bu(w[(size_t)k * N + n]);
  }
}

// ---------------- fused g_u(512->256->256) + attu(512->256->16) ----------
// B-weights read DIRECTLY global->VGPR (pre-swizzled slab, L1/L2-served).
// Only A staged in LDS (double-buffered, 1 barrier/k-step); layer-2 and
// attn loops are barrier-free (hidden read-only in sH; Q per-lane gather).
template <bool IDENT>
__global__ __launch_bounds__(256, 3) void k_fused(
    const int* __restrict__ idx_pairs,
    const int* __restrict__ qidx_arr,
    const short* __restrict__ tab0,
    const short* __restrict__ tab1,
    const short* __restrict__ itembf,
    const short* __restrict__ zp,
    const short* __restrict__ ws1, const float* __restrict__ b1,
    const short* __restrict__ ws2, const float* __restrict__ b2,
    const short* __restrict__ aw1, const float* __restrict__ ab1,
    const short* __restrict__ aw2t, const float* __restrict__ ab2,
    short* __restrict__ Xout, float* __restrict__ miu_out)
{
  __shared__ __align__(16) short smem[20992]; // 2*2048 A dbuf + 16896 sH = 41984 B
  short* sA0 = smem;
  short* sA1 = smem + 2048;
  short* sH  = smem + 4096;

  const int tid = threadIdx.x;
  const int lane = tid & 63;
  const int wave = tid >> 6;
  const int m0 = (int)blockIdx.x << 6;
  const int l15 = lane & 15;
  const int lq = lane >> 4;
  const int nb = wave << 6;

  // A staging: thread t fills quantum t
  const int an = tid >> 2;
  const int kqA = ((tid & 3) - (an >> 1)) & 3;
  const int r = m0 + an;
  const int i0 = idx_pairs[2 * r];
  const int i1 = idx_pairs[2 * r + 1];
  const short* a0 = (IDENT ? (tab0 + (size_t)r * 256) : (tab0 + (size_t)i0 * 256)) + kqA * 8;
  const short* a1 = tab1 + (size_t)i1 * 256 + kqA * 8;

  int pBg[4], pA[4];
#pragma unroll
  for (int i = 0; i < 4; ++i) {
    int n = nb + i * 16 + l15;
    pBg[i] = (n * 4 + ((lq + (n >> 1)) & 3)) * 8;
    int m = i * 16 + l15;
    pA[i] = (m * 4 + ((lq + (m >> 1)) & 3)) * 8;
  }
  const int hOff = lq * 8;

  const f32x4 fz = {0.f, 0.f, 0.f, 0.f};
  f32x4 acc[4][4];
#pragma unroll
  for (int ni = 0; ni < 4; ++ni)
#pragma unroll
    for (int mi = 0; mi < 4; ++mi) acc[ni][mi] = fz;

  short8 wfc[4], wfn[4], rA;

  // ================= g_u layer 1 (K=512, 16 ksteps) =================
  rA = *(const short8*)a0;
#pragma unroll
  for (int i = 0; i < 4; ++i) wfc[i] = *(const short8*)(ws1 + pBg[i]);
  *(short8*)(sA0 + tid * 8) = rA;
  __syncthreads();
  for (int ks = 0; ks < 16; ++ks) {
    short* sAc = (ks & 1) ? sA1 : sA0;
    short* sAn = (ks & 1) ? sA0 : sA1;
    if (ks < 15) {
      const int c = ks + 1;
      rA = *(const short8*)((c < 8) ? (a0 + c * 32) : (a1 + (c - 8) * 32));
      const short* s = ws1 + c * 8192;
#pragma unroll
      for (int i = 0; i < 4; ++i) wfn[i] = *(const short8*)(s + pBg[i]);
    }
    short8 xf[4];
#pragma unroll
    for (int i = 0; i < 4; ++i) xf[i] = *(short8*)(sAc + pA[i]);
#pragma unroll
    for (int ni = 0; ni < 4; ++ni)
#pragma unroll
      for (int mi = 0; mi < 4; ++mi)
        acc[ni][mi] = mfma16(wfc[ni], xf[mi], acc[ni][mi]);
    if (ks < 15) {
      *(short8*)(sAn + tid * 8) = rA;
#pragma unroll
      for (int i = 0; i < 4; ++i) wfc[i] = wfn[i];
    }
    __syncthreads();
  }
  // hidden = relu(+b1) -> sH
#pragma unroll
  for (int ni = 0; ni < 4; ++ni) {
    const int nbase = nb + ni * 16 + lq * 4;
    float4 bb = *(const float4*)(b1 + nbase);
#pragma unroll
    for (int mi = 0; mi < 4; ++mi) {
      const int m = mi * 16 + l15;
      short4v hv;
      hv[0] = (short)f2bu(fmaxf(acc[ni][mi][0] + bb.x, 0.f));
      hv[1] = (short)f2bu(fmaxf(acc[ni][mi][1] + bb.y, 0.f));
      hv[2] = (short)f2bu(fmaxf(acc[ni][mi][2] + bb.z, 0.f));
      hv[3] = (short)f2bu(fmaxf(acc[ni][mi][3] + bb.w, 0.f));
      *(short4v*)(sH + m * 264 + nbase) = hv;
    }
  }
  __syncthreads();   // publish sH

  // ================= g_u layer 2 (K=256, barrier-free) =================
#pragma unroll
  for (int ni = 0; ni < 4; ++ni)
#pragma unroll
    for (int mi = 0; mi < 4; ++mi) acc[ni][mi] = fz;
#pragma unroll
  for (int i = 0; i < 4; ++i) wfc[i] = *(const short8*)(ws2 + pBg[i]);
  for (int ks = 0; ks < 8; ++ks) {
    if (ks < 7) {
      const short* s = ws2 + (ks + 1) * 8192;
#pragma unroll
      for (int i = 0; i < 4; ++i) wfn[i] = *(const short8*)(s + pBg[i]);
    }
    short8 hf[4];
#pragma unroll
    for (int i = 0; i < 4; ++i)
      hf[i] = *(short8*)(sH + (i * 16 + l15) * 264 + ks * 32 + hOff);
#pragma unroll
    for (int ni = 0; ni < 4; ++ni)
#pragma unroll
      for (int mi = 0; mi < 4; ++mi)
        acc[ni][mi] = mfma16(wfc[ni], hf[mi], acc[ni][mi]);
    if (ks < 7) {
#pragma unroll
      for (int i = 0; i < 4; ++i) wfc[i] = wfn[i];
    }
  }
  __syncthreads();   // everyone done reading sH(hidden)

  // f_jt = acc + b2 -> X global + sH
#pragma unroll
  for (int ni = 0; ni < 4; ++ni) {
    const int nbase = nb + ni * 16 + lq * 4;
    float4 bb = *(const float4*)(b2 + nbase);
#pragma unroll
    for (int mi = 0; mi < 4; ++mi) {
      const int m = mi * 16 + l15;
      short4v hv;
      hv[0] = (short)f2bu(acc[ni][mi][0] + bb.x);
      hv[1] = (short)f2bu(acc[ni][mi][1] + bb.y);
      hv[2] = (short)f2bu(acc[ni][mi][2] + bb.z);
      hv[3] = (short)f2bu(acc[ni][mi][3] + bb.w);
      *(short4v*)(sH + m * 264 + nbase) = hv;
      *(short4v*)(Xout + (size_t)(m0 + m) * 256 + nbase) = hv;
    }
  }

  // per-lane Q row pointers (masked -> zero page)
  const short* qp[4];
#pragma unroll
  for (int i = 0; i < 4; ++i) {
    int mrow = m0 + i * 16 + l15;
    int qi2 = qidx_arr[mrow / 12];
    int msk = idx_pairs[2 * mrow];
    qp[i] = ((msk > 0) ? (itembf + (size_t)qi2 * 256) : zp) + lq * 8;
  }
  __syncthreads();   // publish f_jt sH

  // ================= attn layer 1 (K=512, barrier-free) =================
#pragma unroll
  for (int ni = 0; ni < 4; ++ni)
#pragma unroll
    for (int mi = 0; mi < 4; ++mi) acc[ni][mi] = fz;
  short8 xfc[4], xfn[4];
#pragma unroll
  for (int i = 0; i < 4; ++i) {
    wfc[i] = *(const short8*)(aw1 + pBg[i]);
    xfc[i] = *(short8*)(sH + (i * 16 + l15) * 264 + hOff);
  }
  for (int ks = 0; ks < 16; ++ks) {
    if (ks < 15) {
      const int c = ks + 1;
      const short* s = aw1 + c * 8192;
#pragma unroll
      for (int i = 0; i < 4; ++i) wfn[i] = *(const short8*)(s + pBg[i]);
      if (c < 8) {
#pragma unroll
        for (int i = 0; i < 4; ++i)
          xfn[i] = *(short8*)(sH + (i * 16 + l15) * 264 + c * 32 + hOff);
      } else {
#pragma unroll
        for (int i = 0; i < 4; ++i)
          xfn[i] = *(const short8*)(qp[i] + (c - 8) * 32);
      }
    }
#pragma unroll
    for (int ni = 0; ni < 4; ++ni)
#pragma unroll
      for (int mi = 0; mi < 4; ++mi)
        acc[ni][mi] = mfma16(wfc[ni], xfc[mi], acc[ni][mi]);
    if (ks < 15) {
#pragma unroll
      for (int i = 0; i < 4; ++i) { wfc[i] = wfn[i]; xfc[i] = xfn[i]; }
    }
  }
  __syncthreads();   // everyone done reading sH(f_jt)

  // attn hidden = relu(+ab1) -> sH (overwrite)
#pragma unroll
  for (int ni = 0; ni < 4; ++ni) {
    const int nbase = nb + ni * 16 + lq * 4;
    float4 bb = *(const float4*)(ab1 + nbase);
#pragma unroll
    for (int mi = 0; mi < 4; ++mi) {
      const int m = mi * 16 + l15;
      short4v hv;
      hv[0] = (short)f2bu(fmaxf(acc[ni][mi][0] + bb.x, 0.f));
      hv[1] = (short)f2bu(fmaxf(acc[ni][mi][1] + bb.y, 0.f));
      hv[2] = (short)f2bu(fmaxf(acc[ni][mi][2] + bb.z, 0.f));
      hv[3] = (short)f2bu(fmaxf(acc[ni][mi][3] + bb.w, 0.f));
      *(short4v*)(sH + m * 264 + nbase) = hv;
    }
  }
  __syncthreads();

  // ================= attn layer 2 (256 -> 16), W2 direct ==========
  f32x4 a2 = fz;
#pragma unroll
  for (int ks = 0; ks < 8; ++ks) {
    short8 af = *(short8*)(sH + (wave * 16 + l15) * 264 + ks * 32 + hOff);
    short8 bv = *(const short8*)(aw2t + l15 * 256 + ks * 32 + hOff);
    a2 = mfma16(af, bv, a2);
  }
  const float bias = ab2[l15];
#pragma unroll
  for (int j = 0; j < 4; ++j)
    miu_out[(size_t)(m0 + wave * 16 + lq * 4 + j) * 16 + l15] = a2[j] + bias;
}

// ---------------- kappa scores: concat(first[r], itembf[iidx[r]]) -> 16 ---
// Fully direct loads (A rows consecutive, L2-hot), barrier-free main loop.
__global__ __launch_bounds__(256, 3) void k_attonly(
    const short* __restrict__ first,
    const short* __restrict__ itembf,
    const int* __restrict__ iidx,
    const short* __restrict__ aw1, const float* __restrict__ ab1,
    const short* __restrict__ aw2t, const float* __restrict__ ab2,
    float* __restrict__ out)
{
  __shared__ __align__(16) short sH[16896];

  const int tid = threadIdx.x;
  const int lane = tid & 63;
  const int wave = tid >> 6;
  const int m0 = (int)blockIdx.x << 6;
  const int l15 = lane & 15;
  const int lq = lane >> 4;
  const int nb = wave << 6;
  const int hOff = lq * 8;

  const short* fp[4];
  const short* qp[4];
  int pBg[4];
#pragma unroll
  for (int i = 0; i < 4; ++i) {
    int mrow = m0 + i * 16 + l15;
    fp[i] = first + (size_t)mrow * 256 + hOff;
    qp[i] = itembf + (size_t)iidx[mrow] * 256 + hOff;
    int n = nb + i * 16 + l15;
    pBg[i] = (n * 4 + ((lq + (n >> 1)) & 3)) * 8;
  }

  const f32x4 fz = {0.f, 0.f, 0.f, 0.f};
  f32x4 acc[4][4];
#pragma unroll
  for (int ni = 0; ni < 4; ++ni)
#pragma unroll
    for (int mi = 0; mi < 4; ++mi) acc[ni][mi] = fz;

  short8 wfc[4], wfn[4], xfc[4], xfn[4];
#pragma unroll
  for (int i = 0; i < 4; ++i) {
    wfc[i] = *(const short8*)(aw1 + pBg[i]);
    xfc[i] = *(const short8*)(fp[i]);
  }
  for (int ks = 0; ks < 16; ++ks) {
    if (ks < 15) {
      const int c = ks + 1;
      const short* s = aw1 + c * 8192;
#pragma unroll
      for (int i = 0; i < 4; ++i) {
        wfn[i] = *(const short8*)(s + pBg[i]);
        xfn[i] = *(const short8*)((c < 8) ? (fp[i] + c * 32) : (qp[i] + (c - 8) * 32));
      }
    }
#pragma unroll
    for (int ni = 0; ni < 4; ++ni)
#pragma unroll
      for (int mi = 0; mi < 4; ++mi)
        acc[ni][mi] = mfma16(wfc[ni], xfc[mi], acc[ni][mi]);
    if (ks < 15) {
#pragma unroll
      for (int i = 0; i < 4; ++i) { wfc[i] = wfn[i]; xfc[i] = xfn[i]; }
    }
  }
#pragma unroll
  for (int ni = 0; ni < 4; ++ni) {
    const int nbase = nb + ni * 16 + lq * 4;
    float4 bb = *(const float4*)(ab1 + nbase);
#pragma unroll
    for (int mi = 0; mi < 4; ++mi) {
      const int m = mi * 16 + l15;
      short4v hv;
      hv[0] = (short)f2bu(fmaxf(acc[ni][mi][0] + bb.x, 0.f));
      hv[1] = (short)f2bu(fmaxf(acc[ni][mi][1] + bb.y, 0.f));
      hv[2] = (short)f2bu(fmaxf(acc[ni][mi][2] + bb.z, 0.f));
      hv[3] = (short)f2bu(fmaxf(acc[ni][mi][3] + bb.w, 0.f));
      *(short4v*)(sH + m * 264 + nbase) = hv;
    }
  }
  __syncthreads();
  f32x4 a2 = fz;
#pragma unroll
  for (int ks = 0; ks < 8; ++ks) {
    short8 af = *(short8*)(sH + (wave * 16 + l15) * 264 + ks * 32 + hOff);
    short8 bv = *(const short8*)(aw2t + l15 * 256 + ks * 32 + hOff);
    a2 = mfma16(af, bv, a2);
  }
  const float bias = ab2[l15];
#pragma unroll
  for (int j = 0; j < 4; ++j)
    out[(size_t)(m0 + wave * 16 + lq * 4 + j) * 16 + l15] = a2[j] + bias;
}

// ---------------- single-layer GEMM 256->256 + bias + relu (no LDS) -------
__global__ __launch_bounds__(256, 3) void k_gemm1(
    const short* __restrict__ Abf, const short* __restrict__ wt,
    const float* __restrict__ bias, short* __restrict__ out)
{
  const int tid  = threadIdx.x;
  const int lane = tid & 63;
  const int wave = tid >> 6;
  const int m0   = blockIdx.x << 6;
  const int l15  = lane & 15;
  const int lq   = lane >> 4;
  const int rq   = lq << 2;
  const int nb   = wave << 6;
  const int hOff = lq * 8;

  const f32x4 fz = {0.f, 0.f, 0.f, 0.f};
  f32x4 acc[4][4];
#pragma unroll
  for (int mi = 0; mi < 4; ++mi)
#pragma unroll
    for (int ni = 0; ni < 4; ++ni) acc[mi][ni] = fz;

  for (int ks = 0; ks < 8; ++ks) {
    short8 af[4], bv[4];
#pragma unroll
    for (int i = 0; i < 4; ++i) {
      af[i] = *(const short8*)(Abf + (size_t)(m0 + i * 16 + l15) * 256 + ks * 32 + hOff);
      bv[i] = *(const short8*)(wt + (size_t)(nb + i * 16 + l15) * 256 + ks * 32 + hOff);
    }
#pragma unroll
    for (int mi = 0; mi < 4; ++mi)
#pragma unroll
      for (int ni = 0; ni < 4; ++ni)
        acc[mi][ni] = mfma16(af[mi], bv[ni], acc[mi][ni]);
  }

#pragma unroll
  for (int ni = 0; ni < 4; ++ni) {
    const int col = nb + ni * 16 + l15;
    const float b = bias[col];
#pragma unroll
    for (int mi = 0; mi < 4; ++mi)
#pragma unroll
      for (int j = 0; j < 4; ++j) {
        const int row = mi * 16 + rq + j;
        out[(size_t)(m0 + row) * 256 + col] = (short)f2bu(fmaxf(acc[mi][ni][j] + b, 0.f));
      }
  }
}

// ---------------- fused 3-layer comb MLP (unchanged, small) ---------------
__global__ __launch_bounds__(256, 2) void k_comb(
    const short* __restrict__ hju, const short* __restrict__ hjv,
    const short* __restrict__ w1t, const float* __restrict__ b1,
    const short* __restrict__ w2t, const float* __restrict__ b2,
    const short* __restrict__ w3t, const float* __restrict__ b3,
    float* __restrict__ out)
{
  __shared__ __align__(16) short smem[29696];
  short (*A)[40]   = (short(*)[40])smem;
  short (*Bt)[40]  = (short(*)[40])(smem + 2560);
  short (*Hh)[264] = (short(*)[264])(smem + 12800);

  const int tid  = threadIdx.x;
  const int lane = tid & 63;
  const int wave = tid >> 6;
  const int m0   = blockIdx.x << 6;
  const int arow = tid >> 2;
  const int acol8 = (tid & 3) << 3;
  const int lrow = lane & 15;
  const int lk8  = (lane >> 4) << 3;
  const int rq   = (lane >> 4) << 2;
  const int nb   = wave << 6;
  const int r = m0 + arow;

  const f32x4 fz = {0.f, 0.f, 0.f, 0.f};
  f32x4 acc[4][4];
#pragma unroll
  for (int mi = 0; mi < 4; ++mi)
#pragma unroll
    for (int ni = 0; ni < 4; ++ni) acc[mi][ni] = fz;

  for (int ks = 0; ks < 16; ++ks) {
    const int kg = (ks << 5) + acol8;
    short8 av = (kg < 256) ? *(const short8*)(hju + (size_t)r * 256 + kg)
                           : *(const short8*)(hjv + (size_t)r * 256 + (kg - 256));
    *(short8*)&A[arow][acol8] = av;
    const short* wsrc = w1t + tid * 512 + (ks << 5);
    *(short8*)&Bt[tid][0]  = *(const short8*)(wsrc);
    *(short8*)&Bt[tid][8]  = *(const short8*)(wsrc + 8);
    *(short8*)&Bt[tid][16] = *(const short8*)(wsrc + 16);
    *(short8*)&Bt[tid][24] = *(const short8*)(wsrc + 24);
    __syncthreads();
    short8 af[4], bv[4];
#pragma unroll
    for (int mi = 0; mi < 4; ++mi) af[mi] = *(short8*)&A[mi * 16 + lrow][lk8];
#pragma unroll
    for (int ni = 0; ni < 4; ++ni) bv[ni] = *(short8*)&Bt[nb + ni * 16 + lrow][lk8];
#pragma unroll
    for (int mi = 0; mi < 4; ++mi)
#pragma unroll
      for (int ni = 0; ni < 4; ++ni)
        acc[mi][ni] = mfma16(af[mi], bv[ni], acc[mi][ni]);
    __syncthreads();
  }
#pragma unroll
  for (int ni = 0; ni < 4; ++ni) {
    const int col = nb + ni * 16 + lrow;
    const float bias = b1[col];
#pragma unroll
    for (int mi = 0; mi < 4; ++mi)
#pragma unroll
      for (int j = 0; j < 4; ++j)
        Hh[mi * 16 + rq + j][col] = (short)f2bu(fmaxf(acc[mi][ni][j] + bias, 0.f));
  }

#pragma unroll
  for (int mi = 0; mi < 4; ++mi)
#pragma unroll
    for (int ni = 0; ni < 4; ++ni) acc[mi][ni] = fz;
  for (int ks = 0; ks < 8; ++ks) {
    const short* wsrc = w2t + tid * 256 + (ks << 5);
    *(short8*)&Bt[tid][0]  = *(const short8*)(wsrc);
    *(short8*)&Bt[tid][8]  = *(const short8*)(wsrc + 8);
    *(short8*)&Bt[tid][16] = *(const short8*)(wsrc + 16);
    *(short8*)&Bt[tid][24] = *(const short8*)(wsrc + 24);
    __syncthreads();
    short8 af[4], bv[4];
#pragma unroll
    for (int mi = 0; mi < 4; ++mi) af[mi] = *(short8*)&Hh[mi * 16 + lrow][(ks << 5) + lk8];
#pragma unroll
    for (int ni = 0; ni < 4; ++ni) bv[ni] = *(short8*)&Bt[nb + ni * 16 + lrow][lk8];
#pragma unroll
    for (int mi = 0; mi < 4; ++mi)
#pragma unroll
      for (int ni = 0; ni < 4; ++ni)
        acc[mi][ni] = mfma16(af[mi], bv[ni], acc[mi][ni]);
    __syncthreads();
  }
#pragma unroll
  for (int ni = 0; ni < 4; ++ni) {
    const int col = nb + ni * 16 + lrow;
    const float bias = b2[col];
#pragma unroll
    for (int mi = 0; mi < 4; ++mi)
#pragma unroll
      for (int j = 0; j < 4; ++j)
        Hh[mi * 16 + rq + j][col] = (short)f2bu(fmaxf(acc[mi][ni][j] + bias, 0.f));
  }
  __syncthreads();

#pragma unroll
  for (int mi = 0; mi < 4; ++mi)
#pragma unroll
    for (int ni = 0; ni < 4; ++ni) acc[mi][ni] = fz;
  for (int ks = 0; ks < 8; ++ks) {
    const short* wsrc = w3t + tid * 256 + (ks << 5);
    *(short8*)&Bt[tid][0]  = *(const short8*)(wsrc);
    *(short8*)&Bt[tid][8]  = *(const short8*)(wsrc + 8);
    *(short8*)&Bt[tid][16] = *(const short8*)(wsrc + 16);
    *(short8*)&Bt[tid][24] = *(const short8*)(wsrc + 24);
    __syncthreads();
    short8 af[4], bv[4];
#pragma unroll
    for (int mi = 0; mi < 4; ++mi) af[mi] = *(short8*)&Hh[mi * 16 + lrow][(ks << 5) + lk8];
#pragma unroll
    for (int ni = 0; ni < 4; ++ni) bv[ni] = *(short8*)&Bt[nb + ni * 16 + lrow][lk8];
#pragma unroll
    for (int mi = 0; mi < 4; ++mi)
#pragma unroll
      for (int ni = 0; ni < 4; ++ni)
        acc[mi][ni] = mfma16(af[mi], bv[ni], acc[mi][ni]);
    __syncthreads();
  }
#pragma unroll
  for (int ni = 0; ni < 4; ++ni) {
    const int col = nb + ni * 16 + lrow;
    const float bias = b3[col];
#pragma unroll
    for (int mi = 0; mi < 4; ++mi)
#pragma unroll
      for (int j = 0; j < 4; ++j) {
        const int row = mi * 16 + rq + j;
        out[(size_t)(m0 + row) * 256 + col] = fmaxf(acc[mi][ni][j] + bias, 0.f);
      }
  }
}

// ---------------- head MLP + softmax + weighted sum, 16 groups/block ------
__global__ __launch_bounds__(256) void k_headg(
    const float* __restrict__ miu_in,
    const int* __restrict__ mask_src, const int mstride,
    const short* __restrict__ src,
    const float* __restrict__ w1, const float* __restrict__ b1,
    const float* __restrict__ w2, const float* __restrict__ b2,
    short* __restrict__ outp)
{
  __shared__ float in_s[16][192];
  __shared__ float h1[16][96];
  __shared__ float wgt[16][12];

  const int tid = threadIdx.x;
  const int g0 = blockIdx.x * 16;
#pragma unroll
  for (int it = 0; it < 12; ++it) {
    int i = it * 256 + tid;
    ((float*)in_s)[i] = miu_in[(size_t)g0 * 192 + i];
  }
  __syncthreads();
  const int g = tid >> 4, sl = tid & 15;
#pragma unroll
  for (int jj = 0; jj < 6; ++jj) {
    const int j = sl + 16 * jj;
    float s = b1[j];
    for (int k = 0; k < 192; k += 4) {
      s += in_s[g][k]     * w1[k * 96 + j];
      s += in_s[g][k + 1] * w1[(k + 1) * 96 + j];
      s += in_s[g][k + 2] * w1[(k + 2) * 96 + j];
      s += in_s[g][k + 3] * w1[(k + 3) * 96 + j];
    }
    h1[g][j] = fmaxf(s, 0.f);
  }
  __syncthreads();
  if (sl < 12) {
    float s = b2[sl];
#pragma unroll 4
    for (int k = 0; k < 96; ++k) s += h1[g][k] * w2[k * 12 + sl];
    const int gid = g0 + g;
    const int mi = mask_src[(gid * 12 + sl) * mstride];
    wgt[g][sl] = (mi > 0) ? expf(s) : 0.f;
  }
  __syncthreads();
  float tot = 1e-10f;
#pragma unroll
  for (int m = 0; m < 12; ++m) tot += wgt[g][m];
  const float inv = 1.f / tot;

  float o[16];
#pragma unroll
  for (int j = 0; j < 16; ++j) o[j] = 0.f;
  const short* sp = src + ((size_t)(g0 + g) * 12) * 256 + sl * 16;
#pragma unroll
  for (int m = 0; m < 12; ++m) {
    const float wm = wgt[g][m] * inv;
    short8 x0 = *(const short8*)(sp + m * 256);
    short8 x1 = *(const short8*)(sp + m * 256 + 8);
#pragma unroll
    for (int j = 0; j < 8; ++j) {
      o[j]     += wm * b2f((unsigned short)x0[j]);
      o[8 + j] += wm * b2f((unsigned short)x1[j]);
    }
  }
  short8 v0, v1;
#pragma unroll
  for (int j = 0; j < 8; ++j) {
    v0[j] = (short)f2bu(o[j]);
    v1[j] = (short)f2bu(o[8 + j]);
  }
  short* op = outp + (size_t)(g0 + g) * 256 + sl * 16;
  *(short8*)(op) = v0;
  *(short8*)(op + 8) = v1;
}

// =====================================================================
extern "C" void kernel_launch(void* const* d_in, const int* in_sizes, int n_in,
                              void* d_out, int out_size, void* d_ws, size_t ws_size,
                              hipStream_t stream)
{
  (void)in_sizes; (void)n_in; (void)out_size; (void)ws_size;

  const int*   iids = (const int*)d_in[0];
  const int*   iup  = (const int*)d_in[1];
  const int*   iip  = (const int*)d_in[2];
  const int*   iiup = (const int*)d_in[3];
  const float* user_table = (const float*)d_in[4];
  const float* item_table = (const float*)d_in[5];
  const float* rate_table = (const float*)d_in[6];
  const float* g_u_w1 = (const float*)d_in[7];   const float* g_u_b1 = (const float*)d_in[8];
  const float* g_u_w2 = (const float*)d_in[9];   const float* g_u_b2 = (const float*)d_in[10];
  const float* attu_w1 = (const float*)d_in[11]; const float* attu_b1 = (const float*)d_in[12];
  const float* attu_w2 = (const float*)d_in[13]; const float* attu_b2 = (const float*)d_in[14];
  const float* headu_w1 = (const float*)d_in[15]; const float* headu_b1 = (const float*)d_in[16];
  const float* headu_w2 = (const float*)d_in[17]; const float* headu_b2 = (const float*)d_in[18];
  const float* aggi_w = (const float*)d_in[19];  const float* aggi_b = (const float*)d_in[20];
  const float* attii_w1 = (const float*)d_in[21]; const float* attii_b1 = (const float*)d_in[22];
  const float* attii_w2 = (const float*)d_in[23]; const float* attii_b2 = (const float*)d_in[24];
  const float* headii_w1 = (const float*)d_in[25]; const float* headii_b1 = (const float*)d_in[26];
  const float* headii_w2 = (const float*)d_in[27]; const float* headii_b2 = (const float*)d_in[28];
  const float* aggii_w = (const float*)d_in[29]; const float* aggii_b = (const float*)d_in[30];
  const float* comb_w1 = (const float*)d_in[31]; const float* comb_b1 = (const float*)d_in[32];
  const float* comb_w2 = (const float*)d_in[33]; const float* comb_b2 = (const float*)d_in[34];
  const float* comb_w3 = (const float*)d_in[35]; const float* comb_b3 = (const float*)d_in[36];

  const int NIe = 100000 * 256;
  const int M2 = 2048 * 12 * 12;
  const int M1 = 2048 * 12;

  char* wsp = (char*)d_ws;
  size_t off = 0;
  auto alloc = [&](size_t bytes) -> void* {
    void* p = wsp + off;
    off += (bytes + 255) & ~(size_t)255;
    return p;
  };
  short* item_bf = (short*)alloc((size_t)NIe * 2);
  short* rate_bf = (short*)alloc((size_t)6 * 256 * 2);
  short* urows   = (short*)alloc((size_t)M1 * 256 * 2);
  short* zp      = (short*)alloc(512);
  short* sl_gu1   = (short*)alloc((size_t)512 * 256 * 2);
  short* sl_gu2   = (short*)alloc((size_t)256 * 256 * 2);
  short* sl_attu1 = (short*)alloc((size_t)512 * 256 * 2);
  short* sl_attii1= (short*)alloc((size_t)512 * 256 * 2);
  short* wt_attu2 = (short*)alloc((size_t)256 * 16 * 2);
  short* wt_attii2= (short*)alloc((size_t)256 * 16 * 2);
  short* wt_aggi   = (short*)alloc((size_t)256 * 256 * 2);
  short* wt_aggii  = (short*)alloc((size_t)256 * 256 * 2);
  short* wt_comb1  = (short*)alloc((size_t)512 * 256 * 2);
  short* wt_comb2  = (short*)alloc((size_t)256 * 256 * 2);
  short* wt_comb3  = (short*)alloc((size_t)256 * 256 * 2);

  short* X      = (short*)alloc((size_t)M2 * 256 * 2);
  short* FJT    = (short*)alloc((size_t)M1 * 256 * 2);
  float* MIU2   = (float*)alloc((size_t)M2 * 16 * 4);
  float* MIU1   = (float*)alloc((size_t)M1 * 16 * 4);
  float* KAP    = (float*)alloc((size_t)M1 * 16 * 4);
  short* HPRE2  = (short*)alloc((size_t)M1 * 256 * 2);
  short* HOU    = (short*)alloc((size_t)M1 * 256 * 2);
  short* HPREJV = (short*)alloc((size_t)2048 * 256 * 2);
  short* HPRE1  = (short*)alloc((size_t)2048 * 256 * 2);
  short* HJU    = (short*)alloc((size_t)2048 * 256 * 2);
  short* HJV    = (short*)alloc((size_t)2048 * 256 * 2);

  hipMemsetAsync(zp, 0, 512, stream);
  k_cvt<<<NIe / 8 / 256, 256, 0, stream>>>(item_table, item_bf, NIe);
  k_cvt_rows<<<(M1 * 32) / 256, 256, 0, stream>>>(user_table, iup, urows, M1);

  // merged weight prep
  Prep pp;
  int nbk = 0, ei = 0;
  auto addw = [&](const float* s, short* d, int K, int N, int mode) {
    pp.src[ei] = s; pp.dst[ei] = d; pp.K[ei] = K; pp.N[ei] = N; pp.mode[ei] = mode;
    pp.boff[ei] = nbk; nbk += (K * N) / 256; ++ei;
  };
  addw(g_u_w1,   sl_gu1,    512, 256, 0);
  addw(g_u_w2,   sl_gu2,    256, 256, 0);
  addw(attu_w1,  sl_attu1,  512, 256, 0);
  addw(attii_w1, sl_attii1, 512, 256, 0);
  addw(attu_w2,  wt_attu2,  256, 16, 1);
  addw(attii_w2, wt_attii2, 256, 16, 1);
  addw(aggi_w,   wt_aggi,   256, 256, 1);
  addw(aggii_w,  wt_aggii,  256, 256, 1);
  addw(comb_w1,  wt_comb1,  512, 256, 1);
  addw(comb_w2,  wt_comb2,  256, 256, 1);
  addw(comb_w3,  wt_comb3,  256, 256, 1);
  addw(rate_table, rate_bf, 6, 256, 2);
  pp.boff[12] = nbk;
  k_prep<<<nbk, 256, 0, stream>>>(pp);

  k_fused<false><<<M2 / 64, 256, 0, stream>>>(iiup, iip, item_bf, rate_bf, item_bf, zp,
                                              sl_gu1, g_u_b1, sl_gu2, g_u_b2,
                                              sl_attu1, attu_b1, wt_attu2, attu_b2,
                                              X, MIU2);
  k_fused<true><<<M1 / 64, 256, 0, stream>>>(iup, iids, urows, rate_bf, item_bf, zp,
                                             sl_gu1, g_u_b1, sl_gu2, g_u_b2,
                                             sl_attu1, attu_b1, wt_attu2, attu_b2,
                                             FJT, MIU1);

  k_headg<<<M1 / 16, 256, 0, stream>>>(MIU2, iiup, 2, X,
                                       headu_w1, headu_b1, headu_w2, headu_b2, HPRE2);
  k_gemm1<<<M1 / 64, 256, 0, stream>>>(HPRE2, wt_aggi, aggi_b, HOU);
  k_attonly<<<M1 / 64, 256, 0, stream>>>(HOU, item_bf, iip,
                                         sl_attii1, attii_b1, wt_attii2, attii_b2, KAP);
  k_headg<<<2048 / 16, 256, 0, stream>>>(KAP, iip, 1, HOU,
                                         headii_w1, headii_b1, headii_w2, headii_b2, HPREJV);
  k_headg<<<2048 / 16, 256, 0, stream>>>(MIU1, iup, 2, FJT,
                                         headu_w1, headu_b1, headu_w2, headu_b2, HPRE1);
  k_gemm1<<<2048 / 64, 256, 0, stream>>>(HPRE1, wt_aggi, aggi_b, HJU);
  k_gemm1<<<2048 / 64, 256, 0, stream>>>(HPREJV, wt_aggii, aggii_b, HJV);
  k_comb<<<2048 / 64, 256, 0, stream>>>(HJU, HJV, wt_comb1, comb_b1,
                                        wt_comb2, comb_b2, wt_comb3, comb_b3,
                                        (float*)d_out);
}